// Round 1
// baseline (644.253 us; speedup 1.0000x reference)
//
#include <hip/hip_runtime.h>

#define NN 50000
#define NE 800000
#define ET (NE + NN)
#define NEG 0.2f

__device__ __forceinline__ float lrelu(float x) { return x > 0.0f ? x : NEG * x; }
__device__ __forceinline__ float elu1(float x) { return x > 0.0f ? x : __expf(x) - 1.0f; }

// ---------------- GEMM: out[nrows][128] = A[nrows][K] @ W[K][128] ----------------
// W staged fully in LDS (K=256 -> 128KB, K=128 -> 64KB). 256 thr/block:
// cg = tid&31 -> 4 consecutive cols, rg = tid>>5 -> 4 rows (stride 8).
template<int K>
__global__ __launch_bounds__(256) void gemm_kernel(const float* __restrict__ A,
                                                   const float* __restrict__ W,
                                                   float* __restrict__ out, int nrows) {
  __shared__ float Ws[K * 128];
  for (int i = threadIdx.x; i < K * 32; i += 256)
    ((float4*)Ws)[i] = ((const float4*)W)[i];
  __syncthreads();
  const int cg = threadIdx.x & 31;
  const int rg = threadIdx.x >> 5;
  for (int rowbase = blockIdx.x * 32; rowbase < nrows; rowbase += gridDim.x * 32) {
    float acc[4][4] = {};
    int r[4]; bool ok[4];
#pragma unroll
    for (int j = 0; j < 4; ++j) {
      int rr = rowbase + j * 8 + rg;
      ok[j] = rr < nrows;
      r[j] = ok[j] ? rr : (nrows - 1);  // clamp loads, guard stores
    }
    for (int k4 = 0; k4 < K / 4; ++k4) {
      float4 wv[4];
#pragma unroll
      for (int kk = 0; kk < 4; ++kk)
        wv[kk] = *(const float4*)&Ws[(k4 * 4 + kk) * 128 + cg * 4];
#pragma unroll
      for (int j = 0; j < 4; ++j) {
        float4 xv = *(const float4*)&A[(size_t)r[j] * K + k4 * 4];
        acc[j][0] += xv.x * wv[0].x; acc[j][1] += xv.x * wv[0].y;
        acc[j][2] += xv.x * wv[0].z; acc[j][3] += xv.x * wv[0].w;
        acc[j][0] += xv.y * wv[1].x; acc[j][1] += xv.y * wv[1].y;
        acc[j][2] += xv.y * wv[1].z; acc[j][3] += xv.y * wv[1].w;
        acc[j][0] += xv.z * wv[2].x; acc[j][1] += xv.z * wv[2].y;
        acc[j][2] += xv.z * wv[2].z; acc[j][3] += xv.z * wv[2].w;
        acc[j][0] += xv.w * wv[3].x; acc[j][1] += xv.w * wv[3].y;
        acc[j][2] += xv.w * wv[3].z; acc[j][3] += xv.w * wv[3].w;
      }
    }
#pragma unroll
    for (int j = 0; j < 4; ++j) {
      if (ok[j]) {
        float4 o;
        o.x = acc[j][0]; o.y = acc[j][1]; o.z = acc[j][2]; o.w = acc[j][3];
        *(float4*)&out[(size_t)r[j] * 128 + cg * 4] = o;
      }
    }
  }
}

// ---------------- per-node logits: es[n][h] = <h[n,h,:], a_src[h,:]> ----------------
// one wave per node; lane l owns elements l and l+64.
__global__ __launch_bounds__(256) void logits_kernel(const float* __restrict__ h,
                                                     const float* __restrict__ a_src,
                                                     const float* __restrict__ a_dst,
                                                     float* __restrict__ es,
                                                     float* __restrict__ ed) {
  int wid = (blockIdx.x * 256 + threadIdx.x) >> 6;
  if (wid >= NN) return;
  int lane = threadIdx.x & 63;
  float h0 = h[(size_t)wid * 128 + lane];
  float h1 = h[(size_t)wid * 128 + 64 + lane];
  float ps0 = h0 * a_src[lane], ps1 = h1 * a_src[64 + lane];
  float pd0 = h0 * a_dst[lane], pd1 = h1 * a_dst[64 + lane];
#pragma unroll
  for (int off = 1; off < 32; off <<= 1) {  // reduce within 32-lane halves
    ps0 += __shfl_xor(ps0, off); ps1 += __shfl_xor(ps1, off);
    pd0 += __shfl_xor(pd0, off); pd1 += __shfl_xor(pd1, off);
  }
  // lane 0 holds sums of lanes 0..31 (heads 0 and 2); lane 32 holds heads 1 and 3
  if (lane == 0)  { es[wid*4+0]=ps0; es[wid*4+2]=ps1; ed[wid*4+0]=pd0; ed[wid*4+2]=pd1; }
  if (lane == 32) { es[wid*4+1]=ps0; es[wid*4+3]=ps1; ed[wid*4+1]=pd0; ed[wid*4+3]=pd1; }
}

// ---------------- CSR build ----------------
__global__ void count_kernel(const int* __restrict__ ei, int* __restrict__ cnt) {
  int e = blockIdx.x * blockDim.x + threadIdx.x;
  if (e >= ET) return;
  int dst = (e < NE) ? ei[NE + e] : (e - NE);
  atomicAdd(&cnt[dst], 1);
}

__global__ __launch_bounds__(1024) void scan_kernel(const int* __restrict__ cnt,
                                                    int* __restrict__ row_ptr, int n) {
  __shared__ int sm[1024];
  __shared__ int carry_s;
  if (threadIdx.x == 0) { carry_s = 0; row_ptr[0] = 0; }
  __syncthreads();
  for (int base = 0; base < n; base += 4096) {
    int idx = base + threadIdx.x * 4;
    int v[4];
#pragma unroll
    for (int q = 0; q < 4; ++q) v[q] = (idx + q < n) ? cnt[idx + q] : 0;
    int tsum = v[0] + v[1] + v[2] + v[3];
    sm[threadIdx.x] = tsum;
    __syncthreads();
    for (int off = 1; off < 1024; off <<= 1) {
      int t = (threadIdx.x >= off) ? sm[threadIdx.x - off] : 0;
      __syncthreads();
      sm[threadIdx.x] += t;
      __syncthreads();
    }
    int run = sm[threadIdx.x] - tsum + carry_s;  // exclusive prefix + carry
#pragma unroll
    for (int q = 0; q < 4; ++q) {
      run += v[q];
      if (idx + q < n) row_ptr[idx + q + 1] = run;
    }
    __syncthreads();
    if (threadIdx.x == 0) carry_s += sm[1023];
    __syncthreads();
  }
}

__global__ void scatter_kernel(const int* __restrict__ ei, const int* __restrict__ row_ptr,
                               int* __restrict__ fill, int* __restrict__ col) {
  int e = blockIdx.x * blockDim.x + threadIdx.x;
  if (e >= ET) return;
  int src, dst;
  if (e < NE) { src = ei[e]; dst = ei[NE + e]; } else { src = dst = e - NE; }
  int pos = atomicAdd(&fill[dst], 1);
  col[row_ptr[dst] + pos] = src;
}

// ---------------- fused segment-softmax + weighted aggregation + bias + ELU ----------------
// one wave per destination node; lane owns output features lane and lane+64.
__global__ __launch_bounds__(256) void agg_kernel(const float* __restrict__ h,
                                                  const float* __restrict__ es,
                                                  const float* __restrict__ ed,
                                                  const int* __restrict__ row_ptr,
                                                  const int* __restrict__ col,
                                                  const float* __restrict__ bias,
                                                  float* __restrict__ out) {
  int wid = (blockIdx.x * 256 + threadIdx.x) >> 6;
  if (wid >= NN) return;
  int lane = threadIdx.x & 63;
  int start = row_ptr[wid], end = row_ptr[wid + 1];
  float4 edv = *(const float4*)&ed[(size_t)wid * 4];
  float m0 = -1e30f, m1 = -1e30f, m2 = -1e30f, m3 = -1e30f;
  for (int j = start; j < end; ++j) {
    int s = col[j];
    float4 ev = *(const float4*)&es[(size_t)s * 4];
    m0 = fmaxf(m0, lrelu(ev.x + edv.x));
    m1 = fmaxf(m1, lrelu(ev.y + edv.y));
    m2 = fmaxf(m2, lrelu(ev.z + edv.z));
    m3 = fmaxf(m3, lrelu(ev.w + edv.w));
  }
  float s0 = 0.f, s1 = 0.f, s2 = 0.f, s3 = 0.f, acc0 = 0.f, acc1 = 0.f;
  const int hs = lane >> 5;
  for (int j = start; j < end; ++j) {
    int s = col[j];
    float4 ev = *(const float4*)&es[(size_t)s * 4];
    float p0 = __expf(lrelu(ev.x + edv.x) - m0);
    float p1 = __expf(lrelu(ev.y + edv.y) - m1);
    float p2 = __expf(lrelu(ev.z + edv.z) - m2);
    float p3 = __expf(lrelu(ev.w + edv.w) - m3);
    s0 += p0; s1 += p1; s2 += p2; s3 += p3;
    float w0 = hs ? p1 : p0;
    float w1 = hs ? p3 : p2;
    acc0 += h[(size_t)s * 128 + lane] * w0;
    acc1 += h[(size_t)s * 128 + 64 + lane] * w1;
  }
  float d0 = hs ? s1 : s0;
  float d1 = hs ? s3 : s2;
  float o0 = acc0 / d0 + bias[lane];
  float o1 = acc1 / d1 + bias[64 + lane];
  out[(size_t)wid * 128 + lane] = elu1(o0);
  out[(size_t)wid * 128 + 64 + lane] = elu1(o1);
}

extern "C" void kernel_launch(void* const* d_in, const int* in_sizes, int n_in,
                              void* d_out, int out_size, void* d_ws, size_t ws_size,
                              hipStream_t stream) {
  const float* x   = (const float*)d_in[0];
  const int*   ei  = (const int*)d_in[1];   // [2, E] int32 (JAX x64 disabled)
  const float* W1  = (const float*)d_in[2];
  const float* as1 = (const float*)d_in[3];
  const float* ad1 = (const float*)d_in[4];
  const float* b1  = (const float*)d_in[5];
  const float* W2  = (const float*)d_in[6];
  const float* as2 = (const float*)d_in[7];
  const float* ad2 = (const float*)d_in[8];
  const float* b2  = (const float*)d_in[9];

  char* ws = (char*)d_ws;
  float* h    = (float*)(ws);                // 25,600,000 B
  float* h2   = (float*)(ws + 25600000);     // 25,600,000 B
  float* es   = (float*)(ws + 51200000);     //    800,000 B
  float* ed   = (float*)(ws + 52000000);     //    800,000 B
  int*   cnt  = (int*)  (ws + 52800000);     //    200,000 B
  int*   rowp = (int*)  (ws + 53000000);     //    200,016 B
  int*   col  = (int*)  (ws + 53200032);     //  3,400,000 B

  // ---- CSR by destination (same for both layers) ----
  hipMemsetAsync(cnt, 0, NN * sizeof(int), stream);
  int egrid = (ET + 255) / 256;
  count_kernel<<<egrid, 256, 0, stream>>>(ei, cnt);
  scan_kernel<<<1, 1024, 0, stream>>>(cnt, rowp, NN);
  hipMemsetAsync(cnt, 0, NN * sizeof(int), stream);
  scatter_kernel<<<egrid, 256, 0, stream>>>(ei, rowp, cnt, col);

  int ngrid = (NN + 3) / 4;  // one 64-lane wave per node, 4 waves/block

  // ---- layer 1 ----
  gemm_kernel<256><<<512, 256, 0, stream>>>(x, W1, h, NN);
  logits_kernel<<<ngrid, 256, 0, stream>>>(h, as1, ad1, es, ed);
  agg_kernel<<<ngrid, 256, 0, stream>>>(h, es, ed, rowp, col, b1, h2);

  // ---- layer 2 ----
  gemm_kernel<128><<<512, 256, 0, stream>>>(h2, W2, h, NN);
  logits_kernel<<<ngrid, 256, 0, stream>>>(h, as2, ad2, es, ed);
  agg_kernel<<<ngrid, 256, 0, stream>>>(h, es, ed, rowp, col, b2, (float*)d_out);
}

// Round 2
// 455.113 us; speedup vs baseline: 1.4156x; 1.4156x over previous
//
#include <hip/hip_runtime.h>

#define NN 50000
#define NE 800000
#define ET (NE + NN)
#define NEG 0.2f

__device__ __forceinline__ float lrelu(float x) { return x > 0.0f ? x : NEG * x; }
__device__ __forceinline__ float elu1(float x) { return x > 0.0f ? x : __expf(x) - 1.0f; }

// ---------------- GEMM + fused per-node logits ----------------
// out[nrows][128] = A[nrows][K] @ W[K][128];  es/ed[n][h] = <out[n,h,:], a_src/dst[h,:]>
// No LDS: W (<=128KB) is L2-resident and broadcast-read. 256 thr/block:
// cg = tid&31 -> 4 consecutive cols, rg = tid>>5 -> 4 rows (stride 8).
template<int K>
__global__ __launch_bounds__(256) void gemm_kernel(const float* __restrict__ A,
                                                   const float* __restrict__ W,
                                                   const float* __restrict__ a_s,
                                                   const float* __restrict__ a_d,
                                                   float* __restrict__ out,
                                                   float* __restrict__ es,
                                                   float* __restrict__ ed) {
  const int cg = threadIdx.x & 31;
  const int rg = threadIdx.x >> 5;
  const int lane = threadIdx.x & 63;
  const int head = cg >> 3;
  const float4* W4 = (const float4*)W;
  float as[4], ad[4];
#pragma unroll
  for (int c = 0; c < 4; ++c) { as[c] = a_s[cg * 4 + c]; ad[c] = a_d[cg * 4 + c]; }
  for (int rowbase = blockIdx.x * 32; rowbase < NN; rowbase += gridDim.x * 32) {
    float acc[4][4] = {};
    int r[4]; bool ok[4];
#pragma unroll
    for (int j = 0; j < 4; ++j) {
      int rr = rowbase + j * 8 + rg;
      ok[j] = rr < NN;
      r[j] = ok[j] ? rr : (NN - 1);  // clamp loads, guard stores
    }
    for (int k4 = 0; k4 < K / 4; ++k4) {
      float4 wv[4];
#pragma unroll
      for (int kk = 0; kk < 4; ++kk)
        wv[kk] = W4[(k4 * 4 + kk) * 32 + cg];
#pragma unroll
      for (int j = 0; j < 4; ++j) {
        float4 xv = *(const float4*)&A[(size_t)r[j] * K + k4 * 4];
        acc[j][0] += xv.x * wv[0].x; acc[j][1] += xv.x * wv[0].y;
        acc[j][2] += xv.x * wv[0].z; acc[j][3] += xv.x * wv[0].w;
        acc[j][0] += xv.y * wv[1].x; acc[j][1] += xv.y * wv[1].y;
        acc[j][2] += xv.y * wv[1].z; acc[j][3] += xv.y * wv[1].w;
        acc[j][0] += xv.z * wv[2].x; acc[j][1] += xv.z * wv[2].y;
        acc[j][2] += xv.z * wv[2].z; acc[j][3] += xv.z * wv[2].w;
        acc[j][0] += xv.w * wv[3].x; acc[j][1] += xv.w * wv[3].y;
        acc[j][2] += xv.w * wv[3].z; acc[j][3] += xv.w * wv[3].w;
      }
    }
#pragma unroll
    for (int j = 0; j < 4; ++j) {
      // logits partials for this thread's 4 cols, reduced over the 8-lane
      // group sharing (rg, head); ok[j] is uniform within that group.
      float sp = acc[j][0] * as[0] + acc[j][1] * as[1] + acc[j][2] * as[2] + acc[j][3] * as[3];
      float dp = acc[j][0] * ad[0] + acc[j][1] * ad[1] + acc[j][2] * ad[2] + acc[j][3] * ad[3];
#pragma unroll
      for (int off = 1; off < 8; off <<= 1) {
        sp += __shfl_xor(sp, off);
        dp += __shfl_xor(dp, off);
      }
      if (ok[j]) {
        float4 o;
        o.x = acc[j][0]; o.y = acc[j][1]; o.z = acc[j][2]; o.w = acc[j][3];
        *(float4*)&out[(size_t)r[j] * 128 + cg * 4] = o;
        if ((lane & 7) == 0) {
          es[r[j] * 4 + head] = sp;
          ed[r[j] * 4 + head] = dp;
        }
      }
    }
  }
}

// ---------------- CSR build ----------------
__global__ void count_kernel(const int* __restrict__ ei, int* __restrict__ cnt) {
  int e = blockIdx.x * blockDim.x + threadIdx.x;
  if (e >= ET) return;
  int dst = (e < NE) ? ei[NE + e] : (e - NE);
  atomicAdd(&cnt[dst], 1);
}

// single-block wave-shuffle scan: row_ptr = exclusive_scan(cnt), row_ptr[n] = total
__global__ __launch_bounds__(1024) void scan_kernel(const int* __restrict__ cnt,
                                                    int* __restrict__ row_ptr, int n) {
  __shared__ int wsum[16];
  __shared__ int blocktot_s;
  __shared__ int carry_s;
  const int lane = threadIdx.x & 63;
  const int wv = threadIdx.x >> 6;
  if (threadIdx.x == 0) carry_s = 0;
  __syncthreads();
  for (int base = 0; base < n; base += 4096) {
    int idx = base + threadIdx.x * 4;
    int4 v = {0, 0, 0, 0};
    if (idx < n) v = *(const int4*)&cnt[idx];  // n%4==0 -> safe
    int tsum = v.x + v.y + v.z + v.w;
    int sc = tsum;  // inclusive wave scan
#pragma unroll
    for (int off = 1; off < 64; off <<= 1) {
      int t = __shfl_up(sc, off);
      if (lane >= off) sc += t;
    }
    if (lane == 63) wsum[wv] = sc;
    __syncthreads();
    if (wv == 0 && lane < 16) {
      int ws = wsum[lane];
      int si = ws;
#pragma unroll
      for (int off = 1; off < 16; off <<= 1) {
        int t = __shfl_up(si, off);
        if (lane >= off) si += t;
      }
      wsum[lane] = si - ws;  // exclusive wave offset
      if (lane == 15) blocktot_s = si;
    }
    __syncthreads();
    int run = carry_s + wsum[wv] + (sc - tsum);
    if (idx < n) {
      int4 o;
      o.x = run; o.y = run + v.x; o.z = o.y + v.y; o.w = o.z + v.z;
      *(int4*)&row_ptr[idx] = o;  // exclusive prefixes, aligned
    }
    __syncthreads();
    if (threadIdx.x == 0) carry_s += blocktot_s;
    __syncthreads();
  }
  if (threadIdx.x == 0) row_ptr[n] = carry_s;
}

__global__ void scatter_kernel(const int* __restrict__ ei, const int* __restrict__ row_ptr,
                               int* __restrict__ fill, int* __restrict__ col) {
  int e = blockIdx.x * blockDim.x + threadIdx.x;
  if (e >= ET) return;
  int src, dst;
  if (e < NE) { src = ei[e]; dst = ei[NE + e]; } else { src = dst = e - NE; }
  int pos = atomicAdd(&fill[dst], 1);
  col[row_ptr[dst] + pos] = src;
}

// ---------------- per-edge softmax weights (lane-parallel over neighbors) ----------------
// one wave per destination node; lanes split the neighbor list.
// alpha[j] = exp(lrelu(es[col[j]]+ed[dst]) - m[dst]) (un-normalized), inv_s[dst] = 1/sum.
__global__ __launch_bounds__(256) void alpha_kernel(const float4* __restrict__ es4,
                                                    const float4* __restrict__ ed4,
                                                    const int* __restrict__ row_ptr,
                                                    const int* __restrict__ col,
                                                    float4* __restrict__ alpha,
                                                    float4* __restrict__ inv_s) {
  int wid = (blockIdx.x * 256 + threadIdx.x) >> 6;
  if (wid >= NN) return;
  int lane = threadIdx.x & 63;
  int start = row_ptr[wid], end = row_ptr[wid + 1];
  float4 edv = ed4[wid];
  float m0 = -1e30f, m1 = -1e30f, m2 = -1e30f, m3 = -1e30f;
  for (int j = start + lane; j < end; j += 64) {
    float4 ev = es4[col[j]];
    m0 = fmaxf(m0, lrelu(ev.x + edv.x));
    m1 = fmaxf(m1, lrelu(ev.y + edv.y));
    m2 = fmaxf(m2, lrelu(ev.z + edv.z));
    m3 = fmaxf(m3, lrelu(ev.w + edv.w));
  }
#pragma unroll
  for (int off = 32; off; off >>= 1) {
    m0 = fmaxf(m0, __shfl_xor(m0, off)); m1 = fmaxf(m1, __shfl_xor(m1, off));
    m2 = fmaxf(m2, __shfl_xor(m2, off)); m3 = fmaxf(m3, __shfl_xor(m3, off));
  }
  float s0 = 0.f, s1 = 0.f, s2 = 0.f, s3 = 0.f;
  for (int j = start + lane; j < end; j += 64) {
    float4 ev = es4[col[j]];
    float4 p;
    p.x = __expf(lrelu(ev.x + edv.x) - m0);
    p.y = __expf(lrelu(ev.y + edv.y) - m1);
    p.z = __expf(lrelu(ev.z + edv.z) - m2);
    p.w = __expf(lrelu(ev.w + edv.w) - m3);
    alpha[j] = p;
    s0 += p.x; s1 += p.y; s2 += p.z; s3 += p.w;
  }
#pragma unroll
  for (int off = 32; off; off >>= 1) {
    s0 += __shfl_xor(s0, off); s1 += __shfl_xor(s1, off);
    s2 += __shfl_xor(s2, off); s3 += __shfl_xor(s3, off);
  }
  if (lane == 0) {
    float4 iv;
    iv.x = 1.0f / s0; iv.y = 1.0f / s1; iv.z = 1.0f / s2; iv.w = 1.0f / s3;
    inv_s[wid] = iv;
  }
}

// ---------------- weighted aggregation + bias + ELU ----------------
// one wave per destination node; lane owns output features lane and lane+64.
// 4x unrolled: 8 independent gathers in flight per wave.
__global__ __launch_bounds__(256) void agg_kernel(const float* __restrict__ h,
                                                  const float4* __restrict__ alpha,
                                                  const float4* __restrict__ inv_s,
                                                  const int* __restrict__ row_ptr,
                                                  const int* __restrict__ col,
                                                  const float* __restrict__ bias,
                                                  float* __restrict__ out) {
  int wid = (blockIdx.x * 256 + threadIdx.x) >> 6;
  if (wid >= NN) return;
  int lane = threadIdx.x & 63;
  int start = row_ptr[wid], end = row_ptr[wid + 1];
  const int hs = lane >> 5;
  float acc0 = 0.f, acc1 = 0.f;
  int j = start;
  for (; j + 4 <= end; j += 4) {
    int s0 = col[j], s1 = col[j + 1], s2 = col[j + 2], s3 = col[j + 3];
    float4 w0 = alpha[j], w1 = alpha[j + 1], w2 = alpha[j + 2], w3 = alpha[j + 3];
    const float* p0 = h + (size_t)s0 * 128 + lane;
    const float* p1 = h + (size_t)s1 * 128 + lane;
    const float* p2 = h + (size_t)s2 * 128 + lane;
    const float* p3 = h + (size_t)s3 * 128 + lane;
    float a0 = p0[0], b0 = p0[64];
    float a1 = p1[0], b1 = p1[64];
    float a2 = p2[0], b2 = p2[64];
    float a3 = p3[0], b3 = p3[64];
    acc0 += a0 * (hs ? w0.y : w0.x); acc1 += b0 * (hs ? w0.w : w0.z);
    acc0 += a1 * (hs ? w1.y : w1.x); acc1 += b1 * (hs ? w1.w : w1.z);
    acc0 += a2 * (hs ? w2.y : w2.x); acc1 += b2 * (hs ? w2.w : w2.z);
    acc0 += a3 * (hs ? w3.y : w3.x); acc1 += b3 * (hs ? w3.w : w3.z);
  }
  for (; j < end; ++j) {
    int s = col[j];
    float4 w = alpha[j];
    const float* p = h + (size_t)s * 128 + lane;
    acc0 += p[0] * (hs ? w.y : w.x);
    acc1 += p[64] * (hs ? w.w : w.z);
  }
  float4 iv = inv_s[wid];
  float o0 = acc0 * (hs ? iv.y : iv.x) + bias[lane];
  float o1 = acc1 * (hs ? iv.w : iv.z) + bias[64 + lane];
  out[(size_t)wid * 128 + lane] = elu1(o0);
  out[(size_t)wid * 128 + 64 + lane] = elu1(o1);
}

extern "C" void kernel_launch(void* const* d_in, const int* in_sizes, int n_in,
                              void* d_out, int out_size, void* d_ws, size_t ws_size,
                              hipStream_t stream) {
  const float* x   = (const float*)d_in[0];
  const int*   ei  = (const int*)d_in[1];   // [2, E] int32
  const float* W1  = (const float*)d_in[2];
  const float* as1 = (const float*)d_in[3];
  const float* ad1 = (const float*)d_in[4];
  const float* b1  = (const float*)d_in[5];
  const float* W2  = (const float*)d_in[6];
  const float* as2 = (const float*)d_in[7];
  const float* ad2 = (const float*)d_in[8];
  const float* b2  = (const float*)d_in[9];

  char* ws = (char*)d_ws;
  float*  h     = (float*) (ws);                 // 25,600,000 B
  float4* alpha = (float4*)(ws + 25600000);      // 13,600,000 B (ET * 16)
  float*  es    = (float*) (ws + 39200000);      //    800,000 B
  float*  ed    = (float*) (ws + 40000000);      //    800,000 B
  float4* invs  = (float4*)(ws + 40800000);      //    800,000 B
  int*    cnt   = (int*)   (ws + 41600000);      //    200,000 B
  int*    rowp  = (int*)   (ws + 41800000);      //    200,016 B
  int*    col   = (int*)   (ws + 42000064);      //  3,400,000 B
  float*  h2    = (float*) d_out;                // layer-1 output scratch (overwritten by agg2)

  // ---- CSR by destination (same for both layers) ----
  hipMemsetAsync(cnt, 0, NN * sizeof(int), stream);
  int egrid = (ET + 255) / 256;
  count_kernel<<<egrid, 256, 0, stream>>>(ei, cnt);
  scan_kernel<<<1, 1024, 0, stream>>>(cnt, rowp, NN);
  hipMemsetAsync(cnt, 0, NN * sizeof(int), stream);
  scatter_kernel<<<egrid, 256, 0, stream>>>(ei, rowp, cnt, col);

  int ngrid = (NN + 3) / 4;  // one 64-lane wave per node, 4 waves/block

  // ---- layer 1 ----
  gemm_kernel<256><<<1024, 256, 0, stream>>>(x, W1, as1, ad1, h, es, ed);
  alpha_kernel<<<ngrid, 256, 0, stream>>>((const float4*)es, (const float4*)ed, rowp, col, alpha, invs);
  agg_kernel<<<ngrid, 256, 0, stream>>>(h, alpha, invs, rowp, col, b1, h2);

  // ---- layer 2 ----
  gemm_kernel<128><<<1024, 256, 0, stream>>>(h2, W2, as2, ad2, h, es, ed);
  alpha_kernel<<<ngrid, 256, 0, stream>>>((const float4*)es, (const float4*)ed, rowp, col, alpha, invs);
  agg_kernel<<<ngrid, 256, 0, stream>>>(h, alpha, invs, rowp, col, b2, (float*)d_out);
}

// Round 3
// 381.450 us; speedup vs baseline: 1.6890x; 1.1931x over previous
//
#include <hip/hip_runtime.h>

#define NN 50000
#define NE 800000
#define ET (NE + NN)
#define NEG 0.2f

__device__ __forceinline__ float lrelu(float x) { return x > 0.0f ? x : NEG * x; }
__device__ __forceinline__ float elu1(float x) { return x > 0.0f ? x : __expf(x) - 1.0f; }

// ---------------- tiled GEMM + fused per-node logits ----------------
// out[NN][128] = A[NN][K] @ W[K][128]; es/ed[n][h] = <out[n,h,:], a_src/dst[h,:]>
// BM=128, BN=128, BK=32, 256 threads. Thread tile 8x8:
//   tx = tid&15 -> cols tx*8..tx*8+7 ; ty = tid>>4 -> rows ty*8..ty*8+7
// A staged transposed As[k][m] (pad 132 -> bank (4k+m)%32, rows 16B-aligned).
// Register prefetch of next tile overlaps global latency with compute.
template<int K>
__global__ __launch_bounds__(256) void gemm_kernel(const float* __restrict__ A,
                                                   const float* __restrict__ W,
                                                   const float* __restrict__ a_s,
                                                   const float* __restrict__ a_d,
                                                   float* __restrict__ out,
                                                   float* __restrict__ es,
                                                   float* __restrict__ ed) {
  constexpr int NSTEP = K / 32;
  __shared__ float As[32][132];
  __shared__ float Ws[32][128];
  const int tid = threadIdx.x;
  const int tx = tid & 15;
  const int ty = tid >> 4;
  const int lane = tid & 63;
  const int head = tx >> 2;           // 4 threads (8 cols each) per head
  const int row0 = blockIdx.x * 128;

  float as[8], ad[8];
#pragma unroll
  for (int c = 0; c < 8; ++c) { as[c] = a_s[tx * 8 + c]; ad[c] = a_d[tx * 8 + c]; }

  // staging indices: f = tid + i*256 over 1024 float4s per tile
  const int am_[4] = { (tid) >> 3, (tid + 256) >> 3, (tid + 512) >> 3, (tid + 768) >> 3 };
  const int ak_ = (tid & 7) * 4;            // same for all i (256 % 8 == 0)
  const int wk_[4] = { (tid) >> 5, (tid + 256) >> 5, (tid + 512) >> 5, (tid + 768) >> 5 };
  const int wn_ = (tid & 31) * 4;           // same for all i

  float4 areg[4], wreg[4];
  auto load_tiles = [&](int step) {
    const int kb = step * 32;
#pragma unroll
    for (int i = 0; i < 4; ++i) {
      int r = row0 + am_[i];
      r = r < NN ? r : NN - 1;              // clamp (stores are guarded)
      areg[i] = *(const float4*)&A[(size_t)r * K + kb + ak_];
      wreg[i] = *(const float4*)&W[(size_t)(kb + wk_[i]) * 128 + wn_];
    }
  };
  auto store_tiles = [&]() {
#pragma unroll
    for (int i = 0; i < 4; ++i) {
      As[ak_ + 0][am_[i]] = areg[i].x;
      As[ak_ + 1][am_[i]] = areg[i].y;
      As[ak_ + 2][am_[i]] = areg[i].z;
      As[ak_ + 3][am_[i]] = areg[i].w;
      *(float4*)&Ws[wk_[i]][wn_] = wreg[i];
    }
  };

  float acc[8][8] = {};
  load_tiles(0);
  for (int step = 0; step < NSTEP; ++step) {
    __syncthreads();
    store_tiles();
    __syncthreads();
    if (step + 1 < NSTEP) load_tiles(step + 1);
#pragma unroll 4
    for (int k = 0; k < 32; ++k) {
      float4 w0 = *(float4*)&Ws[k][tx * 8];
      float4 w1 = *(float4*)&Ws[k][tx * 8 + 4];
      float4 a0 = *(float4*)&As[k][ty * 8];
      float4 a1 = *(float4*)&As[k][ty * 8 + 4];
      float am[8] = {a0.x, a0.y, a0.z, a0.w, a1.x, a1.y, a1.z, a1.w};
      float wn[8] = {w0.x, w0.y, w0.z, w0.w, w1.x, w1.y, w1.z, w1.w};
#pragma unroll
      for (int j = 0; j < 8; ++j)
#pragma unroll
        for (int c = 0; c < 8; ++c)
          acc[j][c] += am[j] * wn[c];
    }
  }

  // epilogue: store h rows + fused logits (reduce over 4-lane group = one head)
#pragma unroll
  for (int j = 0; j < 8; ++j) {
    int r = row0 + ty * 8 + j;
    float sp = 0.f, dp = 0.f;
#pragma unroll
    for (int c = 0; c < 8; ++c) { sp += acc[j][c] * as[c]; dp += acc[j][c] * ad[c]; }
    sp += __shfl_xor(sp, 1); dp += __shfl_xor(dp, 1);
    sp += __shfl_xor(sp, 2); dp += __shfl_xor(dp, 2);
    if (r < NN) {
      float4 o0, o1;
      o0.x = acc[j][0]; o0.y = acc[j][1]; o0.z = acc[j][2]; o0.w = acc[j][3];
      o1.x = acc[j][4]; o1.y = acc[j][5]; o1.z = acc[j][6]; o1.w = acc[j][7];
      *(float4*)&out[(size_t)r * 128 + tx * 8] = o0;
      *(float4*)&out[(size_t)r * 128 + tx * 8 + 4] = o1;
      if ((lane & 3) == 0) {
        es[r * 4 + head] = sp;
        ed[r * 4 + head] = dp;
      }
    }
  }
}

// ---------------- CSR build ----------------
__global__ void count_kernel(const int* __restrict__ ei, int* __restrict__ cnt) {
  int e = blockIdx.x * blockDim.x + threadIdx.x;
  if (e >= ET) return;
  int dst = (e < NE) ? ei[NE + e] : (e - NE);
  atomicAdd(&cnt[dst], 1);
}

// single-block wave-shuffle scan: row_ptr = exclusive_scan(cnt), row_ptr[n] = total
__global__ __launch_bounds__(1024) void scan_kernel(const int* __restrict__ cnt,
                                                    int* __restrict__ row_ptr, int n) {
  __shared__ int wsum[16];
  __shared__ int blocktot_s;
  __shared__ int carry_s;
  const int lane = threadIdx.x & 63;
  const int wv = threadIdx.x >> 6;
  if (threadIdx.x == 0) carry_s = 0;
  __syncthreads();
  for (int base = 0; base < n; base += 4096) {
    int idx = base + threadIdx.x * 4;
    int4 v = {0, 0, 0, 0};
    if (idx < n) v = *(const int4*)&cnt[idx];  // n%4==0 -> safe
    int tsum = v.x + v.y + v.z + v.w;
    int sc = tsum;  // inclusive wave scan
#pragma unroll
    for (int off = 1; off < 64; off <<= 1) {
      int t = __shfl_up(sc, off);
      if (lane >= off) sc += t;
    }
    if (lane == 63) wsum[wv] = sc;
    __syncthreads();
    if (wv == 0 && lane < 16) {
      int ws = wsum[lane];
      int si = ws;
#pragma unroll
      for (int off = 1; off < 16; off <<= 1) {
        int t = __shfl_up(si, off);
        if (lane >= off) si += t;
      }
      wsum[lane] = si - ws;  // exclusive wave offset
      if (lane == 15) blocktot_s = si;
    }
    __syncthreads();
    int run = carry_s + wsum[wv] + (sc - tsum);
    if (idx < n) {
      int4 o;
      o.x = run; o.y = run + v.x; o.z = o.y + v.y; o.w = o.z + v.z;
      *(int4*)&row_ptr[idx] = o;
    }
    __syncthreads();
    if (threadIdx.x == 0) carry_s += blocktot_s;
    __syncthreads();
  }
  if (threadIdx.x == 0) row_ptr[n] = carry_s;
}

__global__ void scatter_kernel(const int* __restrict__ ei, const int* __restrict__ row_ptr,
                               int* __restrict__ fill, int* __restrict__ col) {
  int e = blockIdx.x * blockDim.x + threadIdx.x;
  if (e >= ET) return;
  int src, dst;
  if (e < NE) { src = ei[e]; dst = ei[NE + e]; } else { src = dst = e - NE; }
  int pos = atomicAdd(&fill[dst], 1);
  col[row_ptr[dst] + pos] = src;
}

// ---------------- per-edge softmax weights (lane-parallel over neighbors) ----------------
__global__ __launch_bounds__(256) void alpha_kernel(const float4* __restrict__ es4,
                                                    const float4* __restrict__ ed4,
                                                    const int* __restrict__ row_ptr,
                                                    const int* __restrict__ col,
                                                    float4* __restrict__ alpha,
                                                    float4* __restrict__ inv_s) {
  int wid = (blockIdx.x * 256 + threadIdx.x) >> 6;
  if (wid >= NN) return;
  int lane = threadIdx.x & 63;
  int start = row_ptr[wid], end = row_ptr[wid + 1];
  float4 edv = ed4[wid];
  float m0 = -1e30f, m1 = -1e30f, m2 = -1e30f, m3 = -1e30f;
  for (int j = start + lane; j < end; j += 64) {
    float4 ev = es4[col[j]];
    m0 = fmaxf(m0, lrelu(ev.x + edv.x));
    m1 = fmaxf(m1, lrelu(ev.y + edv.y));
    m2 = fmaxf(m2, lrelu(ev.z + edv.z));
    m3 = fmaxf(m3, lrelu(ev.w + edv.w));
  }
#pragma unroll
  for (int off = 32; off; off >>= 1) {
    m0 = fmaxf(m0, __shfl_xor(m0, off)); m1 = fmaxf(m1, __shfl_xor(m1, off));
    m2 = fmaxf(m2, __shfl_xor(m2, off)); m3 = fmaxf(m3, __shfl_xor(m3, off));
  }
  float s0 = 0.f, s1 = 0.f, s2 = 0.f, s3 = 0.f;
  for (int j = start + lane; j < end; j += 64) {
    float4 ev = es4[col[j]];
    float4 p;
    p.x = __expf(lrelu(ev.x + edv.x) - m0);
    p.y = __expf(lrelu(ev.y + edv.y) - m1);
    p.z = __expf(lrelu(ev.z + edv.z) - m2);
    p.w = __expf(lrelu(ev.w + edv.w) - m3);
    alpha[j] = p;
    s0 += p.x; s1 += p.y; s2 += p.z; s3 += p.w;
  }
#pragma unroll
  for (int off = 32; off; off >>= 1) {
    s0 += __shfl_xor(s0, off); s1 += __shfl_xor(s1, off);
    s2 += __shfl_xor(s2, off); s3 += __shfl_xor(s3, off);
  }
  if (lane == 0) {
    float4 iv;
    iv.x = 1.0f / s0; iv.y = 1.0f / s1; iv.z = 1.0f / s2; iv.w = 1.0f / s3;
    inv_s[wid] = iv;
  }
}

// ---------------- weighted aggregation + bias + ELU ----------------
__global__ __launch_bounds__(256) void agg_kernel(const float* __restrict__ h,
                                                  const float4* __restrict__ alpha,
                                                  const float4* __restrict__ inv_s,
                                                  const int* __restrict__ row_ptr,
                                                  const int* __restrict__ col,
                                                  const float* __restrict__ bias,
                                                  float* __restrict__ out) {
  int wid = (blockIdx.x * 256 + threadIdx.x) >> 6;
  if (wid >= NN) return;
  int lane = threadIdx.x & 63;
  int start = row_ptr[wid], end = row_ptr[wid + 1];
  const int hs = lane >> 5;
  float acc0 = 0.f, acc1 = 0.f;
  int j = start;
  for (; j + 4 <= end; j += 4) {
    int s0 = col[j], s1 = col[j + 1], s2 = col[j + 2], s3 = col[j + 3];
    float4 w0 = alpha[j], w1 = alpha[j + 1], w2 = alpha[j + 2], w3 = alpha[j + 3];
    const float* p0 = h + (size_t)s0 * 128 + lane;
    const float* p1 = h + (size_t)s1 * 128 + lane;
    const float* p2 = h + (size_t)s2 * 128 + lane;
    const float* p3 = h + (size_t)s3 * 128 + lane;
    float a0 = p0[0], b0 = p0[64];
    float a1 = p1[0], b1 = p1[64];
    float a2 = p2[0], b2 = p2[64];
    float a3 = p3[0], b3 = p3[64];
    acc0 += a0 * (hs ? w0.y : w0.x); acc1 += b0 * (hs ? w0.w : w0.z);
    acc0 += a1 * (hs ? w1.y : w1.x); acc1 += b1 * (hs ? w1.w : w1.z);
    acc0 += a2 * (hs ? w2.y : w2.x); acc1 += b2 * (hs ? w2.w : w2.z);
    acc0 += a3 * (hs ? w3.y : w3.x); acc1 += b3 * (hs ? w3.w : w3.z);
  }
  for (; j < end; ++j) {
    int s = col[j];
    float4 w = alpha[j];
    const float* p = h + (size_t)s * 128 + lane;
    acc0 += p[0] * (hs ? w.y : w.x);
    acc1 += p[64] * (hs ? w.w : w.z);
  }
  float4 iv = inv_s[wid];
  float o0 = acc0 * (hs ? iv.y : iv.x) + bias[lane];
  float o1 = acc1 * (hs ? iv.w : iv.z) + bias[64 + lane];
  out[(size_t)wid * 128 + lane] = elu1(o0);
  out[(size_t)wid * 128 + 64 + lane] = elu1(o1);
}

extern "C" void kernel_launch(void* const* d_in, const int* in_sizes, int n_in,
                              void* d_out, int out_size, void* d_ws, size_t ws_size,
                              hipStream_t stream) {
  const float* x   = (const float*)d_in[0];
  const int*   ei  = (const int*)d_in[1];   // [2, E] int32
  const float* W1  = (const float*)d_in[2];
  const float* as1 = (const float*)d_in[3];
  const float* ad1 = (const float*)d_in[4];
  const float* b1  = (const float*)d_in[5];
  const float* W2  = (const float*)d_in[6];
  const float* as2 = (const float*)d_in[7];
  const float* ad2 = (const float*)d_in[8];
  const float* b2  = (const float*)d_in[9];

  char* ws = (char*)d_ws;
  float*  h     = (float*) (ws);                 // 25,600,000 B
  float4* alpha = (float4*)(ws + 25600000);      // 13,600,000 B (ET * 16)
  float*  es    = (float*) (ws + 39200000);      //    800,000 B
  float*  ed    = (float*) (ws + 40000000);      //    800,000 B
  float4* invs  = (float4*)(ws + 40800000);      //    800,000 B
  int*    cnt   = (int*)   (ws + 41600000);      //    200,000 B
  int*    rowp  = (int*)   (ws + 41800000);      //    200,016 B
  int*    col   = (int*)   (ws + 42000064);      //  3,400,000 B
  float*  h2    = (float*) d_out;                // layer-1 output scratch (overwritten by agg2)

  // ---- CSR by destination (same for both layers) ----
  hipMemsetAsync(cnt, 0, NN * sizeof(int), stream);
  int egrid = (ET + 255) / 256;
  count_kernel<<<egrid, 256, 0, stream>>>(ei, cnt);
  scan_kernel<<<1, 1024, 0, stream>>>(cnt, rowp, NN);
  hipMemsetAsync(cnt, 0, NN * sizeof(int), stream);
  scatter_kernel<<<egrid, 256, 0, stream>>>(ei, rowp, cnt, col);

  int ngrid = (NN + 3) / 4;   // one 64-lane wave per node, 4 waves/block
  int ggrid = (NN + 127) / 128;

  // ---- layer 1 ----
  gemm_kernel<256><<<ggrid, 256, 0, stream>>>(x, W1, as1, ad1, h, es, ed);
  alpha_kernel<<<ngrid, 256, 0, stream>>>((const float4*)es, (const float4*)ed, rowp, col, alpha, invs);
  agg_kernel<<<ngrid, 256, 0, stream>>>(h, alpha, invs, rowp, col, b1, h2);

  // ---- layer 2 ----
  gemm_kernel<128><<<ggrid, 256, 0, stream>>>(h2, W2, as2, ad2, h, es, ed);
  alpha_kernel<<<ngrid, 256, 0, stream>>>((const float4*)es, (const float4*)ed, rowp, col, alpha, invs);
  agg_kernel<<<ngrid, 256, 0, stream>>>(h, alpha, invs, rowp, col, b2, (float*)d_out);
}

// Round 4
// 328.976 us; speedup vs baseline: 1.9584x; 1.1595x over previous
//
#include <hip/hip_runtime.h>

#define NN 50000
#define NE 800000
#define ET (NE + NN)
#define NEG 0.2f

typedef __attribute__((ext_vector_type(4))) float f32x4;
typedef __attribute__((ext_vector_type(8))) short s16x8;

__device__ __forceinline__ float lrelu(float x) { return x > 0.0f ? x : NEG * x; }
__device__ __forceinline__ float elu1(float x) { return x > 0.0f ? x : __expf(x) - 1.0f; }
__device__ __forceinline__ unsigned short f2bf(float f) {  // fp32 -> bf16 RNE
  unsigned u = __float_as_uint(f);
  u += 0x7FFFu + ((u >> 16) & 1u);
  return (unsigned short)(u >> 16);
}
__device__ __forceinline__ float bf2f(unsigned short h) {
  return __uint_as_float(((unsigned)h) << 16);
}

// ---------------- W prep: split fp32 W[K][128] into hi/lo bf16, TRANSPOSED [128][K] ----------------
__global__ void wprep_kernel(const float* __restrict__ W, short* __restrict__ Wth,
                             short* __restrict__ Wtl, int Kdim) {
  int idx = blockIdx.x * 256 + threadIdx.x;
  if (idx >= Kdim * 128) return;
  int k = idx >> 7, n = idx & 127;
  float w = W[idx];
  unsigned short h = f2bf(w);
  unsigned short l = f2bf(w - bf2f(h));
  Wth[n * Kdim + k] = (short)h;
  Wtl[n * Kdim + k] = (short)l;
}

// ---------------- MFMA GEMM (split-bf16, 3 terms) + fused per-node logits ----------------
// out[NN][128] = A[NN][K] @ W[K][128]; es/ed[n][h] = <out[n,h,:], a_src/dst[h,:]>
// BM=64, BN=128(full), BK=32. 256 thr = 4 waves (2m x 2n), each wave 32x64 via
// 2x4 frags of 16x16. A converted fp32->hi/lo bf16 during staging (A streamed once).
// LDS tiles [row][32] bf16 (row stride 64B): frag ds_read_b128 is bank-balanced.
template<int K>
__global__ __launch_bounds__(256) void gemm_mfma(const float* __restrict__ A,
                                                 const short* __restrict__ Bth,
                                                 const short* __restrict__ Btl,
                                                 const float* __restrict__ a_s,
                                                 const float* __restrict__ a_d,
                                                 float* __restrict__ out,
                                                 float* __restrict__ es,
                                                 float* __restrict__ ed) {
  constexpr int NSTEP = K / 32;
  __shared__ short Ah[64 * 32], Al[64 * 32];
  __shared__ short Bh[128 * 32], Bl[128 * 32];
  const int tid = threadIdx.x;
  const int lane = tid & 63;
  const int wv = tid >> 6;
  const int wm = wv >> 1, wn = wv & 1;
  const int row0 = blockIdx.x * 64;
  const int srow = tid >> 2;   // staging row 0..63
  const int skc = tid & 3;     // staging k-chunk of 8

  f32x4 acc[2][4];
#pragma unroll
  for (int i = 0; i < 2; ++i)
#pragma unroll
    for (int j = 0; j < 4; ++j) acc[i][j] = (f32x4){0.f, 0.f, 0.f, 0.f};

  for (int s = 0; s < NSTEP; ++s) {
    __syncthreads();
    {  // stage A: 8 fp32 -> 8 (hi,lo) bf16 pairs
      int grow = row0 + srow; grow = grow < NN ? grow : NN - 1;  // clamp; stores guarded
      const float* ap = &A[(size_t)grow * K + s * 32 + skc * 8];
      float4 x0 = *(const float4*)ap;
      float4 x1 = *(const float4*)(ap + 4);
      float xs[8] = {x0.x, x0.y, x0.z, x0.w, x1.x, x1.y, x1.z, x1.w};
      int hi[4], lo[4];
#pragma unroll
      for (int q = 0; q < 4; ++q) {
        unsigned short h0 = f2bf(xs[2 * q]);
        unsigned short l0 = f2bf(xs[2 * q] - bf2f(h0));
        unsigned short h1 = f2bf(xs[2 * q + 1]);
        unsigned short l1 = f2bf(xs[2 * q + 1] - bf2f(h1));
        hi[q] = (int)(((unsigned)h1 << 16) | h0);
        lo[q] = (int)(((unsigned)l1 << 16) | l0);
      }
      *(int4*)&Ah[srow * 32 + skc * 8] = make_int4(hi[0], hi[1], hi[2], hi[3]);
      *(int4*)&Al[srow * 32 + skc * 8] = make_int4(lo[0], lo[1], lo[2], lo[3]);
    }
#pragma unroll
    for (int rr = 0; rr < 2; ++rr) {  // stage B (pre-split, pre-transposed bf16)
      int n = srow + rr * 64;
      *(int4*)&Bh[n * 32 + skc * 8] = *(const int4*)&Bth[(size_t)n * K + s * 32 + skc * 8];
      *(int4*)&Bl[n * 32 + skc * 8] = *(const int4*)&Btl[(size_t)n * K + s * 32 + skc * 8];
    }
    __syncthreads();
    const int fr = lane & 15;
    const int fk = (lane >> 4) * 8;
    s16x8 ah[2], al[2], bh[4], bl[4];
#pragma unroll
    for (int mf = 0; mf < 2; ++mf) {
      int r = wm * 32 + mf * 16 + fr;
      ah[mf] = *(const s16x8*)&Ah[r * 32 + fk];
      al[mf] = *(const s16x8*)&Al[r * 32 + fk];
    }
#pragma unroll
    for (int nf = 0; nf < 4; ++nf) {
      int n = wn * 64 + nf * 16 + fr;
      bh[nf] = *(const s16x8*)&Bh[n * 32 + fk];
      bl[nf] = *(const s16x8*)&Bl[n * 32 + fk];
    }
#pragma unroll
    for (int mf = 0; mf < 2; ++mf)
#pragma unroll
      for (int nf = 0; nf < 4; ++nf) {
        acc[mf][nf] = __builtin_amdgcn_mfma_f32_16x16x32_bf16(ah[mf], bh[nf], acc[mf][nf], 0, 0, 0);
        acc[mf][nf] = __builtin_amdgcn_mfma_f32_16x16x32_bf16(ah[mf], bl[nf], acc[mf][nf], 0, 0, 0);
        acc[mf][nf] = __builtin_amdgcn_mfma_f32_16x16x32_bf16(al[mf], bh[nf], acc[mf][nf], 0, 0, 0);
      }
  }

  // epilogue: C/D layout col=lane&15, row=(lane>>4)*4+r (guide m89/m91-verified)
  const int fr = lane & 15;
  const int fg = lane >> 4;
  float asr[4], adr[4];
#pragma unroll
  for (int nf = 0; nf < 4; ++nf) {
    int c = wn * 64 + nf * 16 + fr;
    asr[nf] = a_s[c]; adr[nf] = a_d[c];
  }
#pragma unroll
  for (int mf = 0; mf < 2; ++mf) {
#pragma unroll
    for (int r = 0; r < 4; ++r) {
      int row = row0 + wm * 32 + mf * 16 + fg * 4 + r;
      float sp0 = acc[mf][0][r] * asr[0] + acc[mf][1][r] * asr[1];  // head wn*2
      float sp1 = acc[mf][2][r] * asr[2] + acc[mf][3][r] * asr[3];  // head wn*2+1
      float dp0 = acc[mf][0][r] * adr[0] + acc[mf][1][r] * adr[1];
      float dp1 = acc[mf][2][r] * adr[2] + acc[mf][3][r] * adr[3];
#pragma unroll
      for (int off = 1; off < 16; off <<= 1) {  // reduce over the 16 cols (stays in 16-lane group)
        sp0 += __shfl_xor(sp0, off); sp1 += __shfl_xor(sp1, off);
        dp0 += __shfl_xor(dp0, off); dp1 += __shfl_xor(dp1, off);
      }
      if (row < NN) {
#pragma unroll
        for (int nf = 0; nf < 4; ++nf)
          out[(size_t)row * 128 + wn * 64 + nf * 16 + fr] = acc[mf][nf][r];
        if (fr == 0) {
          es[row * 4 + wn * 2 + 0] = sp0;
          es[row * 4 + wn * 2 + 1] = sp1;
          ed[row * 4 + wn * 2 + 0] = dp0;
          ed[row * 4 + wn * 2 + 1] = dp1;
        }
      }
    }
  }
}

// ---------------- CSR build ----------------
__global__ void count_kernel(const int* __restrict__ ei, int* __restrict__ cnt) {
  int e = blockIdx.x * blockDim.x + threadIdx.x;
  if (e >= ET) return;
  int dst = (e < NE) ? ei[NE + e] : (e - NE);
  atomicAdd(&cnt[dst], 1);
}

__global__ __launch_bounds__(1024) void scan_kernel(const int* __restrict__ cnt,
                                                    int* __restrict__ row_ptr, int n) {
  __shared__ int wsum[16];
  __shared__ int blocktot_s;
  __shared__ int carry_s;
  const int lane = threadIdx.x & 63;
  const int wv = threadIdx.x >> 6;
  if (threadIdx.x == 0) carry_s = 0;
  __syncthreads();
  for (int base = 0; base < n; base += 4096) {
    int idx = base + threadIdx.x * 4;
    int4 v = {0, 0, 0, 0};
    if (idx < n) v = *(const int4*)&cnt[idx];
    int tsum = v.x + v.y + v.z + v.w;
    int sc = tsum;
#pragma unroll
    for (int off = 1; off < 64; off <<= 1) {
      int t = __shfl_up(sc, off);
      if (lane >= off) sc += t;
    }
    if (lane == 63) wsum[wv] = sc;
    __syncthreads();
    if (wv == 0 && lane < 16) {
      int ws = wsum[lane];
      int si = ws;
#pragma unroll
      for (int off = 1; off < 16; off <<= 1) {
        int t = __shfl_up(si, off);
        if (lane >= off) si += t;
      }
      wsum[lane] = si - ws;
      if (lane == 15) blocktot_s = si;
    }
    __syncthreads();
    int run = carry_s + wsum[wv] + (sc - tsum);
    if (idx < n) {
      int4 o;
      o.x = run; o.y = run + v.x; o.z = o.y + v.y; o.w = o.z + v.z;
      *(int4*)&row_ptr[idx] = o;
    }
    __syncthreads();
    if (threadIdx.x == 0) carry_s += blocktot_s;
    __syncthreads();
  }
  if (threadIdx.x == 0) row_ptr[n] = carry_s;
}

__global__ void scatter_kernel(const int* __restrict__ ei, const int* __restrict__ row_ptr,
                               int* __restrict__ fill, int* __restrict__ col) {
  int e = blockIdx.x * blockDim.x + threadIdx.x;
  if (e >= ET) return;
  int src, dst;
  if (e < NE) { src = ei[e]; dst = ei[NE + e]; } else { src = dst = e - NE; }
  int pos = atomicAdd(&fill[dst], 1);
  col[row_ptr[dst] + pos] = src;
}

// ---------------- per-edge softmax weights (lane-parallel over neighbors) ----------------
__global__ __launch_bounds__(256) void alpha_kernel(const float4* __restrict__ es4,
                                                    const float4* __restrict__ ed4,
                                                    const int* __restrict__ row_ptr,
                                                    const int* __restrict__ col,
                                                    float4* __restrict__ alpha,
                                                    float4* __restrict__ inv_s) {
  int wid = (blockIdx.x * 256 + threadIdx.x) >> 6;
  if (wid >= NN) return;
  int lane = threadIdx.x & 63;
  int start = row_ptr[wid], end = row_ptr[wid + 1];
  float4 edv = ed4[wid];
  float m0 = -1e30f, m1 = -1e30f, m2 = -1e30f, m3 = -1e30f;
  for (int j = start + lane; j < end; j += 64) {
    float4 ev = es4[col[j]];
    m0 = fmaxf(m0, lrelu(ev.x + edv.x));
    m1 = fmaxf(m1, lrelu(ev.y + edv.y));
    m2 = fmaxf(m2, lrelu(ev.z + edv.z));
    m3 = fmaxf(m3, lrelu(ev.w + edv.w));
  }
#pragma unroll
  for (int off = 32; off; off >>= 1) {
    m0 = fmaxf(m0, __shfl_xor(m0, off)); m1 = fmaxf(m1, __shfl_xor(m1, off));
    m2 = fmaxf(m2, __shfl_xor(m2, off)); m3 = fmaxf(m3, __shfl_xor(m3, off));
  }
  float s0 = 0.f, s1 = 0.f, s2 = 0.f, s3 = 0.f;
  for (int j = start + lane; j < end; j += 64) {
    float4 ev = es4[col[j]];
    float4 p;
    p.x = __expf(lrelu(ev.x + edv.x) - m0);
    p.y = __expf(lrelu(ev.y + edv.y) - m1);
    p.z = __expf(lrelu(ev.z + edv.z) - m2);
    p.w = __expf(lrelu(ev.w + edv.w) - m3);
    alpha[j] = p;
    s0 += p.x; s1 += p.y; s2 += p.z; s3 += p.w;
  }
#pragma unroll
  for (int off = 32; off; off >>= 1) {
    s0 += __shfl_xor(s0, off); s1 += __shfl_xor(s1, off);
    s2 += __shfl_xor(s2, off); s3 += __shfl_xor(s3, off);
  }
  if (lane == 0) {
    float4 iv;
    iv.x = 1.0f / s0; iv.y = 1.0f / s1; iv.z = 1.0f / s2; iv.w = 1.0f / s3;
    inv_s[wid] = iv;
  }
}

// ---------------- weighted aggregation + bias + ELU ----------------
__global__ __launch_bounds__(256) void agg_kernel(const float* __restrict__ h,
                                                  const float4* __restrict__ alpha,
                                                  const float4* __restrict__ inv_s,
                                                  const int* __restrict__ row_ptr,
                                                  const int* __restrict__ col,
                                                  const float* __restrict__ bias,
                                                  float* __restrict__ out) {
  int wid = (blockIdx.x * 256 + threadIdx.x) >> 6;
  if (wid >= NN) return;
  int lane = threadIdx.x & 63;
  int start = row_ptr[wid], end = row_ptr[wid + 1];
  const int hs = lane >> 5;
  float acc0 = 0.f, acc1 = 0.f;
  int j = start;
  for (; j + 4 <= end; j += 4) {
    int s0 = col[j], s1 = col[j + 1], s2 = col[j + 2], s3 = col[j + 3];
    float4 w0 = alpha[j], w1 = alpha[j + 1], w2 = alpha[j + 2], w3 = alpha[j + 3];
    const float* p0 = h + (size_t)s0 * 128 + lane;
    const float* p1 = h + (size_t)s1 * 128 + lane;
    const float* p2 = h + (size_t)s2 * 128 + lane;
    const float* p3 = h + (size_t)s3 * 128 + lane;
    float a0 = p0[0], b0 = p0[64];
    float a1 = p1[0], b1 = p1[64];
    float a2 = p2[0], b2 = p2[64];
    float a3 = p3[0], b3 = p3[64];
    acc0 += a0 * (hs ? w0.y : w0.x); acc1 += b0 * (hs ? w0.w : w0.z);
    acc0 += a1 * (hs ? w1.y : w1.x); acc1 += b1 * (hs ? w1.w : w1.z);
    acc0 += a2 * (hs ? w2.y : w2.x); acc1 += b2 * (hs ? w2.w : w2.z);
    acc0 += a3 * (hs ? w3.y : w3.x); acc1 += b3 * (hs ? w3.w : w3.z);
  }
  for (; j < end; ++j) {
    int s = col[j];
    float4 w = alpha[j];
    const float* p = h + (size_t)s * 128 + lane;
    acc0 += p[0] * (hs ? w.y : w.x);
    acc1 += p[64] * (hs ? w.w : w.z);
  }
  float4 iv = inv_s[wid];
  float o0 = acc0 * (hs ? iv.y : iv.x) + bias[lane];
  float o1 = acc1 * (hs ? iv.w : iv.z) + bias[64 + lane];
  out[(size_t)wid * 128 + lane] = elu1(o0);
  out[(size_t)wid * 128 + 64 + lane] = elu1(o1);
}

extern "C" void kernel_launch(void* const* d_in, const int* in_sizes, int n_in,
                              void* d_out, int out_size, void* d_ws, size_t ws_size,
                              hipStream_t stream) {
  const float* x   = (const float*)d_in[0];
  const int*   ei  = (const int*)d_in[1];   // [2, E] int32
  const float* W1  = (const float*)d_in[2];
  const float* as1 = (const float*)d_in[3];
  const float* ad1 = (const float*)d_in[4];
  const float* b1  = (const float*)d_in[5];
  const float* W2  = (const float*)d_in[6];
  const float* as2 = (const float*)d_in[7];
  const float* ad2 = (const float*)d_in[8];
  const float* b2  = (const float*)d_in[9];

  char* ws = (char*)d_ws;
  float*  h     = (float*) (ws);                 // 25,600,000 B
  float4* alpha = (float4*)(ws + 25600000);      // 13,600,000 B (ET * 16)
  float*  es    = (float*) (ws + 39200000);      //    800,000 B
  float*  ed    = (float*) (ws + 40000000);      //    800,000 B
  float4* invs  = (float4*)(ws + 40800000);      //    800,000 B
  int*    cnt   = (int*)   (ws + 41600000);      //    200,000 B
  int*    rowp  = (int*)   (ws + 41800000);      //    200,016 B
  int*    col   = (int*)   (ws + 42000064);      //  3,400,000 B
  short*  wt1h  = (short*) (ws + 45400064);      //     65,536 B
  short*  wt1l  = (short*) (ws + 45465600);      //     65,536 B
  short*  wt2h  = (short*) (ws + 45531136);      //     32,768 B
  short*  wt2l  = (short*) (ws + 45563904);      //     32,768 B
  float*  h2    = (float*) d_out;                // layer-1 output scratch (overwritten by agg2)

  // ---- W split/transpose prep ----
  wprep_kernel<<<128, 256, 0, stream>>>(W1, wt1h, wt1l, 256);
  wprep_kernel<<<64, 256, 0, stream>>>(W2, wt2h, wt2l, 128);

  // ---- CSR by destination (same for both layers) ----
  hipMemsetAsync(cnt, 0, NN * sizeof(int), stream);
  int egrid = (ET + 255) / 256;
  count_kernel<<<egrid, 256, 0, stream>>>(ei, cnt);
  scan_kernel<<<1, 1024, 0, stream>>>(cnt, rowp, NN);
  hipMemsetAsync(cnt, 0, NN * sizeof(int), stream);
  scatter_kernel<<<egrid, 256, 0, stream>>>(ei, rowp, cnt, col);

  int ngrid = (NN + 3) / 4;        // one 64-lane wave per node
  int ggrid = (NN + 63) / 64;      // 782 blocks

  // ---- layer 1 ----
  gemm_mfma<256><<<ggrid, 256, 0, stream>>>(x, wt1h, wt1l, as1, ad1, h, es, ed);
  alpha_kernel<<<ngrid, 256, 0, stream>>>((const float4*)es, (const float4*)ed, rowp, col, alpha, invs);
  agg_kernel<<<ngrid, 256, 0, stream>>>(h, alpha, invs, rowp, col, b1, h2);

  // ---- layer 2 ----
  gemm_mfma<128><<<ggrid, 256, 0, stream>>>(h2, wt2h, wt2l, as2, ad2, h, es, ed);
  alpha_kernel<<<ngrid, 256, 0, stream>>>((const float4*)es, (const float4*)ed, rowp, col, alpha, invs);
  agg_kernel<<<ngrid, 256, 0, stream>>>(h, alpha, invs, rowp, col, b2, (float*)d_out);
}

// Round 5
// 289.196 us; speedup vs baseline: 2.2277x; 1.1376x over previous
//
#include <hip/hip_runtime.h>
#include <hip/hip_fp16.h>

#define NN 50000
#define NE 800000
#define ET (NE + NN)
#define NEG 0.2f

typedef __attribute__((ext_vector_type(4))) float f32x4;
typedef __attribute__((ext_vector_type(8))) short s16x8;

__device__ __forceinline__ float lrelu(float x) { return x > 0.0f ? x : NEG * x; }
__device__ __forceinline__ float elu1(float x) { return x > 0.0f ? x : __expf(x) - 1.0f; }
__device__ __forceinline__ unsigned short f2bf(float f) {  // fp32 -> bf16 RNE
  unsigned u = __float_as_uint(f);
  u += 0x7FFFu + ((u >> 16) & 1u);
  return (unsigned short)(u >> 16);
}
__device__ __forceinline__ float bf2f(unsigned short h) {
  return __uint_as_float(((unsigned)h) << 16);
}

// ---------------- W prep: split fp32 W[K][128] into hi/lo bf16, TRANSPOSED [128][K] ----------------
__global__ void wprep_kernel(const float* __restrict__ W, short* __restrict__ Wth,
                             short* __restrict__ Wtl, int Kdim) {
  int idx = blockIdx.x * 256 + threadIdx.x;
  if (idx >= Kdim * 128) return;
  int k = idx >> 7, n = idx & 127;
  float w = W[idx];
  unsigned short h = f2bf(w);
  unsigned short l = f2bf(w - bf2f(h));
  Wth[n * Kdim + k] = (short)h;
  Wtl[n * Kdim + k] = (short)l;
}

// ---------------- MFMA GEMM (split-bf16, 3 terms) + fused per-node logits ----------------
// outh(fp16)[NN][128] = A[NN][K] @ W[K][128]; es/ed[n][h] = <out[n,h,:], a_src/dst[h,:]>
// BM=64, BN=128(full), BK=32. 256 thr = 4 waves (2m x 2n), each wave 32x64 via
// 2x4 frags of 16x16. A converted fp32->hi/lo bf16 during staging (A streamed once).
template<int K>
__global__ __launch_bounds__(256) void gemm_mfma(const float* __restrict__ A,
                                                 const short* __restrict__ Bth,
                                                 const short* __restrict__ Btl,
                                                 const float* __restrict__ a_s,
                                                 const float* __restrict__ a_d,
                                                 __half* __restrict__ outh,
                                                 float* __restrict__ es,
                                                 float* __restrict__ ed) {
  constexpr int NSTEP = K / 32;
  __shared__ short Ah[64 * 32], Al[64 * 32];
  __shared__ short Bh[128 * 32], Bl[128 * 32];
  const int tid = threadIdx.x;
  const int lane = tid & 63;
  const int wv = tid >> 6;
  const int wm = wv >> 1, wn = wv & 1;
  const int row0 = blockIdx.x * 64;
  const int srow = tid >> 2;   // staging row 0..63
  const int skc = tid & 3;     // staging k-chunk of 8

  f32x4 acc[2][4];
#pragma unroll
  for (int i = 0; i < 2; ++i)
#pragma unroll
    for (int j = 0; j < 4; ++j) acc[i][j] = (f32x4){0.f, 0.f, 0.f, 0.f};

  for (int s = 0; s < NSTEP; ++s) {
    __syncthreads();
    {  // stage A: 8 fp32 -> 8 (hi,lo) bf16 pairs
      int grow = row0 + srow; grow = grow < NN ? grow : NN - 1;  // clamp; stores guarded
      const float* ap = &A[(size_t)grow * K + s * 32 + skc * 8];
      float4 x0 = *(const float4*)ap;
      float4 x1 = *(const float4*)(ap + 4);
      float xs[8] = {x0.x, x0.y, x0.z, x0.w, x1.x, x1.y, x1.z, x1.w};
      int hi[4], lo[4];
#pragma unroll
      for (int q = 0; q < 4; ++q) {
        unsigned short h0 = f2bf(xs[2 * q]);
        unsigned short l0 = f2bf(xs[2 * q] - bf2f(h0));
        unsigned short h1 = f2bf(xs[2 * q + 1]);
        unsigned short l1 = f2bf(xs[2 * q + 1] - bf2f(h1));
        hi[q] = (int)(((unsigned)h1 << 16) | h0);
        lo[q] = (int)(((unsigned)l1 << 16) | l0);
      }
      *(int4*)&Ah[srow * 32 + skc * 8] = make_int4(hi[0], hi[1], hi[2], hi[3]);
      *(int4*)&Al[srow * 32 + skc * 8] = make_int4(lo[0], lo[1], lo[2], lo[3]);
    }
#pragma unroll
    for (int rr = 0; rr < 2; ++rr) {  // stage B (pre-split, pre-transposed bf16)
      int n = srow + rr * 64;
      *(int4*)&Bh[n * 32 + skc * 8] = *(const int4*)&Bth[(size_t)n * K + s * 32 + skc * 8];
      *(int4*)&Bl[n * 32 + skc * 8] = *(const int4*)&Btl[(size_t)n * K + s * 32 + skc * 8];
    }
    __syncthreads();
    const int fr = lane & 15;
    const int fk = (lane >> 4) * 8;
    s16x8 ah[2], al[2], bh[4], bl[4];
#pragma unroll
    for (int mf = 0; mf < 2; ++mf) {
      int r = wm * 32 + mf * 16 + fr;
      ah[mf] = *(const s16x8*)&Ah[r * 32 + fk];
      al[mf] = *(const s16x8*)&Al[r * 32 + fk];
    }
#pragma unroll
    for (int nf = 0; nf < 4; ++nf) {
      int n = wn * 64 + nf * 16 + fr;
      bh[nf] = *(const s16x8*)&Bh[n * 32 + fk];
      bl[nf] = *(const s16x8*)&Bl[n * 32 + fk];
    }
#pragma unroll
    for (int mf = 0; mf < 2; ++mf)
#pragma unroll
      for (int nf = 0; nf < 4; ++nf) {
        acc[mf][nf] = __builtin_amdgcn_mfma_f32_16x16x32_bf16(ah[mf], bh[nf], acc[mf][nf], 0, 0, 0);
        acc[mf][nf] = __builtin_amdgcn_mfma_f32_16x16x32_bf16(ah[mf], bl[nf], acc[mf][nf], 0, 0, 0);
        acc[mf][nf] = __builtin_amdgcn_mfma_f32_16x16x32_bf16(al[mf], bh[nf], acc[mf][nf], 0, 0, 0);
      }
  }

  // epilogue: C/D layout col=lane&15, row=(lane>>4)*4+r
  const int fr = lane & 15;
  const int fg = lane >> 4;
  float asr[4], adr[4];
#pragma unroll
  for (int nf = 0; nf < 4; ++nf) {
    int c = wn * 64 + nf * 16 + fr;
    asr[nf] = a_s[c]; adr[nf] = a_d[c];
  }
#pragma unroll
  for (int mf = 0; mf < 2; ++mf) {
#pragma unroll
    for (int r = 0; r < 4; ++r) {
      int row = row0 + wm * 32 + mf * 16 + fg * 4 + r;
      float sp0 = acc[mf][0][r] * asr[0] + acc[mf][1][r] * asr[1];  // head wn*2
      float sp1 = acc[mf][2][r] * asr[2] + acc[mf][3][r] * asr[3];  // head wn*2+1
      float dp0 = acc[mf][0][r] * adr[0] + acc[mf][1][r] * adr[1];
      float dp1 = acc[mf][2][r] * adr[2] + acc[mf][3][r] * adr[3];
#pragma unroll
      for (int off = 1; off < 16; off <<= 1) {  // reduce over the 16 cols (stays in 16-lane group)
        sp0 += __shfl_xor(sp0, off); sp1 += __shfl_xor(sp1, off);
        dp0 += __shfl_xor(dp0, off); dp1 += __shfl_xor(dp1, off);
      }
      if (row < NN) {
#pragma unroll
        for (int nf = 0; nf < 4; ++nf)
          outh[(size_t)row * 128 + wn * 64 + nf * 16 + fr] = __float2half(acc[mf][nf][r]);
        if (fr == 0) {
          es[row * 4 + wn * 2 + 0] = sp0;
          es[row * 4 + wn * 2 + 1] = sp1;
          ed[row * 4 + wn * 2 + 0] = dp0;
          ed[row * 4 + wn * 2 + 1] = dp1;
        }
      }
    }
  }
}

// ---------------- CSR build ----------------
__global__ void count_kernel(const int* __restrict__ ei, int* __restrict__ cnt) {
  int e = blockIdx.x * blockDim.x + threadIdx.x;
  if (e >= ET) return;
  int dst = (e < NE) ? ei[NE + e] : (e - NE);
  atomicAdd(&cnt[dst], 1);
}

__global__ __launch_bounds__(1024) void scan_kernel(const int* __restrict__ cnt,
                                                    int* __restrict__ row_ptr, int n) {
  __shared__ int wsum[16];
  __shared__ int blocktot_s;
  __shared__ int carry_s;
  const int lane = threadIdx.x & 63;
  const int wv = threadIdx.x >> 6;
  if (threadIdx.x == 0) carry_s = 0;
  __syncthreads();
  for (int base = 0; base < n; base += 4096) {
    int idx = base + threadIdx.x * 4;
    int4 v = {0, 0, 0, 0};
    if (idx < n) v = *(const int4*)&cnt[idx];
    int tsum = v.x + v.y + v.z + v.w;
    int sc = tsum;
#pragma unroll
    for (int off = 1; off < 64; off <<= 1) {
      int t = __shfl_up(sc, off);
      if (lane >= off) sc += t;
    }
    if (lane == 63) wsum[wv] = sc;
    __syncthreads();
    if (wv == 0 && lane < 16) {
      int ws = wsum[lane];
      int si = ws;
#pragma unroll
      for (int off = 1; off < 16; off <<= 1) {
        int t = __shfl_up(si, off);
        if (lane >= off) si += t;
      }
      wsum[lane] = si - ws;
      if (lane == 15) blocktot_s = si;
    }
    __syncthreads();
    int run = carry_s + wsum[wv] + (sc - tsum);
    if (idx < n) {
      int4 o;
      o.x = run; o.y = run + v.x; o.z = o.y + v.y; o.w = o.z + v.z;
      *(int4*)&row_ptr[idx] = o;
    }
    __syncthreads();
    if (threadIdx.x == 0) carry_s += blocktot_s;
    __syncthreads();
  }
  if (threadIdx.x == 0) row_ptr[n] = carry_s;
}

__global__ void scatter_kernel(const int* __restrict__ ei, const int* __restrict__ row_ptr,
                               int* __restrict__ fill, int* __restrict__ col) {
  int e = blockIdx.x * blockDim.x + threadIdx.x;
  if (e >= ET) return;
  int src, dst;
  if (e < NE) { src = ei[e]; dst = ei[NE + e]; } else { src = dst = e - NE; }
  int pos = atomicAdd(&fill[dst], 1);
  col[row_ptr[dst] + pos] = src;
}

// ---------------- per-edge softmax weights (lane-parallel over neighbors) ----------------
// Registers cache the first 128 neighbors' es gathers (covers ~all nodes).
__global__ __launch_bounds__(256) void alpha_kernel(const float4* __restrict__ es4,
                                                    const float4* __restrict__ ed4,
                                                    const int* __restrict__ row_ptr,
                                                    const int* __restrict__ col,
                                                    float4* __restrict__ alpha,
                                                    float4* __restrict__ inv_s) {
  int wid = (blockIdx.x * 256 + threadIdx.x) >> 6;
  if (wid >= NN) return;
  int lane = threadIdx.x & 63;
  int start = row_ptr[wid], end = row_ptr[wid + 1];
  float4 edv = ed4[wid];
  const int j0 = start + lane, j1 = j0 + 64;
  const bool v0 = j0 < end, v1 = j1 < end;
  float4 e0, e1;
  if (v0) e0 = es4[col[j0]];
  if (v1) e1 = es4[col[j1]];
  float m0 = -1e30f, m1 = -1e30f, m2 = -1e30f, m3 = -1e30f;
  if (v0) {
    m0 = fmaxf(m0, lrelu(e0.x + edv.x)); m1 = fmaxf(m1, lrelu(e0.y + edv.y));
    m2 = fmaxf(m2, lrelu(e0.z + edv.z)); m3 = fmaxf(m3, lrelu(e0.w + edv.w));
  }
  if (v1) {
    m0 = fmaxf(m0, lrelu(e1.x + edv.x)); m1 = fmaxf(m1, lrelu(e1.y + edv.y));
    m2 = fmaxf(m2, lrelu(e1.z + edv.z)); m3 = fmaxf(m3, lrelu(e1.w + edv.w));
  }
  for (int j = j1 + 64; j < end; j += 64) {  // rare: degree > 128
    float4 ev = es4[col[j]];
    m0 = fmaxf(m0, lrelu(ev.x + edv.x)); m1 = fmaxf(m1, lrelu(ev.y + edv.y));
    m2 = fmaxf(m2, lrelu(ev.z + edv.z)); m3 = fmaxf(m3, lrelu(ev.w + edv.w));
  }
#pragma unroll
  for (int off = 32; off; off >>= 1) {
    m0 = fmaxf(m0, __shfl_xor(m0, off)); m1 = fmaxf(m1, __shfl_xor(m1, off));
    m2 = fmaxf(m2, __shfl_xor(m2, off)); m3 = fmaxf(m3, __shfl_xor(m3, off));
  }
  float s0 = 0.f, s1 = 0.f, s2 = 0.f, s3 = 0.f;
  if (v0) {
    float4 p;
    p.x = __expf(lrelu(e0.x + edv.x) - m0); p.y = __expf(lrelu(e0.y + edv.y) - m1);
    p.z = __expf(lrelu(e0.z + edv.z) - m2); p.w = __expf(lrelu(e0.w + edv.w) - m3);
    alpha[j0] = p;
    s0 += p.x; s1 += p.y; s2 += p.z; s3 += p.w;
  }
  if (v1) {
    float4 p;
    p.x = __expf(lrelu(e1.x + edv.x) - m0); p.y = __expf(lrelu(e1.y + edv.y) - m1);
    p.z = __expf(lrelu(e1.z + edv.z) - m2); p.w = __expf(lrelu(e1.w + edv.w) - m3);
    alpha[j1] = p;
    s0 += p.x; s1 += p.y; s2 += p.z; s3 += p.w;
  }
  for (int j = j1 + 64; j < end; j += 64) {
    float4 ev = es4[col[j]];
    float4 p;
    p.x = __expf(lrelu(ev.x + edv.x) - m0); p.y = __expf(lrelu(ev.y + edv.y) - m1);
    p.z = __expf(lrelu(ev.z + edv.z) - m2); p.w = __expf(lrelu(ev.w + edv.w) - m3);
    alpha[j] = p;
    s0 += p.x; s1 += p.y; s2 += p.z; s3 += p.w;
  }
#pragma unroll
  for (int off = 32; off; off >>= 1) {
    s0 += __shfl_xor(s0, off); s1 += __shfl_xor(s1, off);
    s2 += __shfl_xor(s2, off); s3 += __shfl_xor(s3, off);
  }
  if (lane == 0) {
    float4 iv;
    iv.x = 1.0f / s0; iv.y = 1.0f / s1; iv.z = 1.0f / s2; iv.w = 1.0f / s3;
    inv_s[wid] = iv;
  }
}

// ---------------- weighted aggregation + bias + ELU ----------------
// one wave per destination node; lane owns adjacent features 2l, 2l+1 (same head = l>>4).
// One __half2 load per lane per edge; weight is a broadcast scalar load.
__global__ __launch_bounds__(256) void agg_kernel(const __half* __restrict__ h,
                                                  const float* __restrict__ alpha,
                                                  const float* __restrict__ inv_s,
                                                  const int* __restrict__ row_ptr,
                                                  const int* __restrict__ col,
                                                  const float* __restrict__ bias,
                                                  float* __restrict__ out) {
  int wid = (blockIdx.x * 256 + threadIdx.x) >> 6;
  if (wid >= NN) return;
  int lane = threadIdx.x & 63;
  int start = row_ptr[wid], end = row_ptr[wid + 1];
  const int hd = lane >> 4;
  float acc0 = 0.f, acc1 = 0.f;
  int j = start;
  for (; j + 4 <= end; j += 4) {
    int s0 = col[j], s1 = col[j + 1], s2 = col[j + 2], s3 = col[j + 3];
    float w0 = alpha[(size_t)j * 4 + hd];
    float w1 = alpha[(size_t)(j + 1) * 4 + hd];
    float w2 = alpha[(size_t)(j + 2) * 4 + hd];
    float w3 = alpha[(size_t)(j + 3) * 4 + hd];
    __half2 v0 = *(const __half2*)&h[(size_t)s0 * 128 + 2 * lane];
    __half2 v1 = *(const __half2*)&h[(size_t)s1 * 128 + 2 * lane];
    __half2 v2 = *(const __half2*)&h[(size_t)s2 * 128 + 2 * lane];
    __half2 v3 = *(const __half2*)&h[(size_t)s3 * 128 + 2 * lane];
    float2 f0 = __half22float2(v0), f1 = __half22float2(v1);
    float2 f2 = __half22float2(v2), f3 = __half22float2(v3);
    acc0 += f0.x * w0; acc1 += f0.y * w0;
    acc0 += f1.x * w1; acc1 += f1.y * w1;
    acc0 += f2.x * w2; acc1 += f2.y * w2;
    acc0 += f3.x * w3; acc1 += f3.y * w3;
  }
  for (; j < end; ++j) {
    int s = col[j];
    float w = alpha[(size_t)j * 4 + hd];
    __half2 v = *(const __half2*)&h[(size_t)s * 128 + 2 * lane];
    float2 f = __half22float2(v);
    acc0 += f.x * w; acc1 += f.y * w;
  }
  float iv = inv_s[wid * 4 + hd];
  float o0 = acc0 * iv + bias[2 * lane];
  float o1 = acc1 * iv + bias[2 * lane + 1];
  float2 o; o.x = elu1(o0); o.y = elu1(o1);
  *(float2*)&out[(size_t)wid * 128 + 2 * lane] = o;
}

extern "C" void kernel_launch(void* const* d_in, const int* in_sizes, int n_in,
                              void* d_out, int out_size, void* d_ws, size_t ws_size,
                              hipStream_t stream) {
  const float* x   = (const float*)d_in[0];
  const int*   ei  = (const int*)d_in[1];   // [2, E] int32
  const float* W1  = (const float*)d_in[2];
  const float* as1 = (const float*)d_in[3];
  const float* ad1 = (const float*)d_in[4];
  const float* b1  = (const float*)d_in[5];
  const float* W2  = (const float*)d_in[6];
  const float* as2 = (const float*)d_in[7];
  const float* ad2 = (const float*)d_in[8];
  const float* b2  = (const float*)d_in[9];

  char* ws = (char*)d_ws;
  __half* h     = (__half*)(ws);                 // 12,800,000 B (fp16 h table)
  float4* alpha = (float4*)(ws + 12800000);      // 13,600,000 B (ET * 16)
  float*  es    = (float*) (ws + 26400000);      //    800,000 B
  float*  ed    = (float*) (ws + 27200000);      //    800,000 B
  float4* invs  = (float4*)(ws + 28000000);      //    800,000 B
  int*    cnt   = (int*)   (ws + 28800000);      //    200,000 B
  int*    rowp  = (int*)   (ws + 29000000);      //    200,016 B
  int*    col   = (int*)   (ws + 29200064);      //  3,400,000 B
  short*  wt1h  = (short*) (ws + 32600064);      //     65,536 B
  short*  wt1l  = (short*) (ws + 32665600);      //     65,536 B
  short*  wt2h  = (short*) (ws + 32731136);      //     32,768 B
  short*  wt2l  = (short*) (ws + 32763904);      //     32,768 B
  float*  h2    = (float*) d_out;                // layer-1 output scratch (overwritten by agg2)

  // ---- W split/transpose prep ----
  wprep_kernel<<<128, 256, 0, stream>>>(W1, wt1h, wt1l, 256);
  wprep_kernel<<<64, 256, 0, stream>>>(W2, wt2h, wt2l, 128);

  // ---- CSR by destination (same for both layers) ----
  hipMemsetAsync(cnt, 0, NN * sizeof(int), stream);
  int egrid = (ET + 255) / 256;
  count_kernel<<<egrid, 256, 0, stream>>>(ei, cnt);
  scan_kernel<<<1, 1024, 0, stream>>>(cnt, rowp, NN);
  hipMemsetAsync(cnt, 0, NN * sizeof(int), stream);
  scatter_kernel<<<egrid, 256, 0, stream>>>(ei, rowp, cnt, col);

  int ngrid = (NN + 3) / 4;        // one 64-lane wave per node
  int ggrid = (NN + 63) / 64;      // 782 blocks

  // ---- layer 1 ----
  gemm_mfma<256><<<ggrid, 256, 0, stream>>>(x, wt1h, wt1l, as1, ad1, h, es, ed);
  alpha_kernel<<<ngrid, 256, 0, stream>>>((const float4*)es, (const float4*)ed, rowp, col, alpha, invs);
  agg_kernel<<<ngrid, 256, 0, stream>>>(h, (const float*)alpha, (const float*)invs, rowp, col, b1, h2);

  // ---- layer 2 ----
  gemm_mfma<128><<<ggrid, 256, 0, stream>>>(h2, wt2h, wt2l, as2, ad2, h, es, ed);
  alpha_kernel<<<ngrid, 256, 0, stream>>>((const float4*)es, (const float4*)ed, rowp, col, alpha, invs);
  agg_kernel<<<ngrid, 256, 0, stream>>>(h, (const float*)alpha, (const float*)invs, rowp, col, b2, (float*)d_out);
}

// Round 6
// 255.132 us; speedup vs baseline: 2.5252x; 1.1335x over previous
//
#include <hip/hip_runtime.h>
#include <hip/hip_fp16.h>

#define NN 50000
#define NE 800000
#define ET (NE + NN)
#define NEG 0.2f

typedef __attribute__((ext_vector_type(4))) float f32x4;
typedef __attribute__((ext_vector_type(8))) short s16x8;

__device__ __forceinline__ float lrelu(float x) { return x > 0.0f ? x : NEG * x; }
__device__ __forceinline__ float elu1(float x) { return x > 0.0f ? x : __expf(x) - 1.0f; }
__device__ __forceinline__ unsigned short f2bf(float f) {  // fp32 -> bf16 RNE
  unsigned u = __float_as_uint(f);
  u += 0x7FFFu + ((u >> 16) & 1u);
  return (unsigned short)(u >> 16);
}
__device__ __forceinline__ float bf2f(unsigned short h) {
  return __uint_as_float(((unsigned)h) << 16);
}
__device__ __forceinline__ unsigned pack2h(float a, float b) {
  __half2 t = __floats2half2_rn(a, b);
  return *(unsigned*)&t;
}

// ---------------- W prep: split fp32 W[K][128] into hi/lo bf16, TRANSPOSED [128][K] ----------------
__global__ void wprep_kernel(const float* __restrict__ W, short* __restrict__ Wth,
                             short* __restrict__ Wtl, int Kdim) {
  int idx = blockIdx.x * 256 + threadIdx.x;
  if (idx >= Kdim * 128) return;
  int k = idx >> 7, n = idx & 127;
  float w = W[idx];
  unsigned short h = f2bf(w);
  unsigned short l = f2bf(w - bf2f(h));
  Wth[n * Kdim + k] = (short)h;
  Wtl[n * Kdim + k] = (short)l;
}

// ---------------- MFMA GEMM (split-bf16, 3 terms) + fused per-node logits ----------------
template<int K>
__global__ __launch_bounds__(256) void gemm_mfma(const float* __restrict__ A,
                                                 const short* __restrict__ Bth,
                                                 const short* __restrict__ Btl,
                                                 const float* __restrict__ a_s,
                                                 const float* __restrict__ a_d,
                                                 __half* __restrict__ outh,
                                                 float* __restrict__ es,
                                                 float* __restrict__ ed) {
  constexpr int NSTEP = K / 32;
  __shared__ short Ah[64 * 32], Al[64 * 32];
  __shared__ short Bh[128 * 32], Bl[128 * 32];
  const int tid = threadIdx.x;
  const int lane = tid & 63;
  const int wv = tid >> 6;
  const int wm = wv >> 1, wn = wv & 1;
  const int row0 = blockIdx.x * 64;
  const int srow = tid >> 2;   // staging row 0..63
  const int skc = tid & 3;     // staging k-chunk of 8

  f32x4 acc[2][4];
#pragma unroll
  for (int i = 0; i < 2; ++i)
#pragma unroll
    for (int j = 0; j < 4; ++j) acc[i][j] = (f32x4){0.f, 0.f, 0.f, 0.f};

  for (int s = 0; s < NSTEP; ++s) {
    __syncthreads();
    {  // stage A: 8 fp32 -> 8 (hi,lo) bf16 pairs
      int grow = row0 + srow; grow = grow < NN ? grow : NN - 1;  // clamp; stores guarded
      const float* ap = &A[(size_t)grow * K + s * 32 + skc * 8];
      float4 x0 = *(const float4*)ap;
      float4 x1 = *(const float4*)(ap + 4);
      float xs[8] = {x0.x, x0.y, x0.z, x0.w, x1.x, x1.y, x1.z, x1.w};
      int hi[4], lo[4];
#pragma unroll
      for (int q = 0; q < 4; ++q) {
        unsigned short h0 = f2bf(xs[2 * q]);
        unsigned short l0 = f2bf(xs[2 * q] - bf2f(h0));
        unsigned short h1 = f2bf(xs[2 * q + 1]);
        unsigned short l1 = f2bf(xs[2 * q + 1] - bf2f(h1));
        hi[q] = (int)(((unsigned)h1 << 16) | h0);
        lo[q] = (int)(((unsigned)l1 << 16) | l0);
      }
      *(int4*)&Ah[srow * 32 + skc * 8] = make_int4(hi[0], hi[1], hi[2], hi[3]);
      *(int4*)&Al[srow * 32 + skc * 8] = make_int4(lo[0], lo[1], lo[2], lo[3]);
    }
#pragma unroll
    for (int rr = 0; rr < 2; ++rr) {  // stage B (pre-split, pre-transposed bf16)
      int n = srow + rr * 64;
      *(int4*)&Bh[n * 32 + skc * 8] = *(const int4*)&Bth[(size_t)n * K + s * 32 + skc * 8];
      *(int4*)&Bl[n * 32 + skc * 8] = *(const int4*)&Btl[(size_t)n * K + s * 32 + skc * 8];
    }
    __syncthreads();
    const int fr = lane & 15;
    const int fk = (lane >> 4) * 8;
    s16x8 ah[2], al[2], bh[4], bl[4];
#pragma unroll
    for (int mf = 0; mf < 2; ++mf) {
      int r = wm * 32 + mf * 16 + fr;
      ah[mf] = *(const s16x8*)&Ah[r * 32 + fk];
      al[mf] = *(const s16x8*)&Al[r * 32 + fk];
    }
#pragma unroll
    for (int nf = 0; nf < 4; ++nf) {
      int n = wn * 64 + nf * 16 + fr;
      bh[nf] = *(const s16x8*)&Bh[n * 32 + fk];
      bl[nf] = *(const s16x8*)&Bl[n * 32 + fk];
    }
#pragma unroll
    for (int mf = 0; mf < 2; ++mf)
#pragma unroll
      for (int nf = 0; nf < 4; ++nf) {
        acc[mf][nf] = __builtin_amdgcn_mfma_f32_16x16x32_bf16(ah[mf], bh[nf], acc[mf][nf], 0, 0, 0);
        acc[mf][nf] = __builtin_amdgcn_mfma_f32_16x16x32_bf16(ah[mf], bl[nf], acc[mf][nf], 0, 0, 0);
        acc[mf][nf] = __builtin_amdgcn_mfma_f32_16x16x32_bf16(al[mf], bh[nf], acc[mf][nf], 0, 0, 0);
      }
  }

  // epilogue: C/D layout col=lane&15, row=(lane>>4)*4+r
  const int fr = lane & 15;
  const int fg = lane >> 4;
  float asr[4], adr[4];
#pragma unroll
  for (int nf = 0; nf < 4; ++nf) {
    int c = wn * 64 + nf * 16 + fr;
    asr[nf] = a_s[c]; adr[nf] = a_d[c];
  }
#pragma unroll
  for (int mf = 0; mf < 2; ++mf) {
#pragma unroll
    for (int r = 0; r < 4; ++r) {
      int row = row0 + wm * 32 + mf * 16 + fg * 4 + r;
      float sp0 = acc[mf][0][r] * asr[0] + acc[mf][1][r] * asr[1];  // head wn*2
      float sp1 = acc[mf][2][r] * asr[2] + acc[mf][3][r] * asr[3];  // head wn*2+1
      float dp0 = acc[mf][0][r] * adr[0] + acc[mf][1][r] * adr[1];
      float dp1 = acc[mf][2][r] * adr[2] + acc[mf][3][r] * adr[3];
#pragma unroll
      for (int off = 1; off < 16; off <<= 1) {  // reduce over the 16 cols
        sp0 += __shfl_xor(sp0, off); sp1 += __shfl_xor(sp1, off);
        dp0 += __shfl_xor(dp0, off); dp1 += __shfl_xor(dp1, off);
      }
      if (row < NN) {
#pragma unroll
        for (int nf = 0; nf < 4; ++nf)
          outh[(size_t)row * 128 + wn * 64 + nf * 16 + fr] = __float2half(acc[mf][nf][r]);
        if (fr == 0) {
          es[row * 4 + wn * 2 + 0] = sp0;
          es[row * 4 + wn * 2 + 1] = sp1;
          ed[row * 4 + wn * 2 + 0] = dp0;
          ed[row * 4 + wn * 2 + 1] = dp1;
        }
      }
    }
  }
}

// ---------------- CSR build: count + rank (the only atomic pass) ----------------
__global__ void count_rank_kernel(const int* __restrict__ ei, int* __restrict__ cnt,
                                  int* __restrict__ rank) {
  int e = blockIdx.x * blockDim.x + threadIdx.x;
  if (e >= ET) return;
  int dst = (e < NE) ? ei[NE + e] : (e - NE);
  rank[e] = atomicAdd(&cnt[dst], 1);   // coalesced store of rank; order-nondeterminism
                                       // only permutes within-neighborhood order (FP-noise level)
}

__global__ __launch_bounds__(1024) void scan_kernel(const int* __restrict__ cnt,
                                                    int* __restrict__ row_ptr, int n) {
  __shared__ int wsum[16];
  __shared__ int blocktot_s;
  __shared__ int carry_s;
  const int lane = threadIdx.x & 63;
  const int wv = threadIdx.x >> 6;
  if (threadIdx.x == 0) carry_s = 0;
  __syncthreads();
  for (int base = 0; base < n; base += 4096) {
    int idx = base + threadIdx.x * 4;
    int4 v = {0, 0, 0, 0};
    if (idx < n) v = *(const int4*)&cnt[idx];
    int tsum = v.x + v.y + v.z + v.w;
    int sc = tsum;
#pragma unroll
    for (int off = 1; off < 64; off <<= 1) {
      int t = __shfl_up(sc, off);
      if (lane >= off) sc += t;
    }
    if (lane == 63) wsum[wv] = sc;
    __syncthreads();
    if (wv == 0 && lane < 16) {
      int ws = wsum[lane];
      int si = ws;
#pragma unroll
      for (int off = 1; off < 16; off <<= 1) {
        int t = __shfl_up(si, off);
        if (lane >= off) si += t;
      }
      wsum[lane] = si - ws;
      if (lane == 15) blocktot_s = si;
    }
    __syncthreads();
    int run = carry_s + wsum[wv] + (sc - tsum);
    if (idx < n) {
      int4 o;
      o.x = run; o.y = run + v.x; o.z = o.y + v.y; o.w = o.z + v.z;
      *(int4*)&row_ptr[idx] = o;
    }
    __syncthreads();
    if (threadIdx.x == 0) carry_s += blocktot_s;
    __syncthreads();
  }
  if (threadIdx.x == 0) row_ptr[n] = carry_s;
}

// atomic-free scatter: position = row_ptr[dst] + rank[e]
__global__ void scatter_kernel(const int* __restrict__ ei, const int* __restrict__ row_ptr,
                               const int* __restrict__ rank, int* __restrict__ col) {
  int e = blockIdx.x * blockDim.x + threadIdx.x;
  if (e >= ET) return;
  int src, dst;
  if (e < NE) { src = ei[e]; dst = ei[NE + e]; } else { src = dst = e - NE; }
  col[row_ptr[dst] + rank[e]] = src;
}

// ---------------- per-edge NORMALIZED softmax weights -> fp16x4 (8B/edge) ----------------
// one wave per destination node; lanes split the neighbor list; first-128 logits
// register-cached so the normalize pass needs no re-gather (deg>128 re-gathers; ~never).
__global__ __launch_bounds__(256) void alpha_kernel(const float4* __restrict__ es4,
                                                    const float4* __restrict__ ed4,
                                                    const int* __restrict__ row_ptr,
                                                    const int* __restrict__ col,
                                                    __half* __restrict__ alphaH) {
  int wid = (blockIdx.x * 256 + threadIdx.x) >> 6;
  if (wid >= NN) return;
  int lane = threadIdx.x & 63;
  int start = row_ptr[wid], end = row_ptr[wid + 1];
  float4 edv = ed4[wid];
  const int j0 = start + lane, j1 = j0 + 64;
  const bool v0 = j0 < end, v1 = j1 < end;
  float4 e0, e1;
  if (v0) e0 = es4[col[j0]];
  if (v1) e1 = es4[col[j1]];
  float m0 = -1e30f, m1 = -1e30f, m2 = -1e30f, m3 = -1e30f;
  if (v0) {
    m0 = fmaxf(m0, lrelu(e0.x + edv.x)); m1 = fmaxf(m1, lrelu(e0.y + edv.y));
    m2 = fmaxf(m2, lrelu(e0.z + edv.z)); m3 = fmaxf(m3, lrelu(e0.w + edv.w));
  }
  if (v1) {
    m0 = fmaxf(m0, lrelu(e1.x + edv.x)); m1 = fmaxf(m1, lrelu(e1.y + edv.y));
    m2 = fmaxf(m2, lrelu(e1.z + edv.z)); m3 = fmaxf(m3, lrelu(e1.w + edv.w));
  }
  for (int j = j1 + 64; j < end; j += 64) {  // rare: degree > 128
    float4 ev = es4[col[j]];
    m0 = fmaxf(m0, lrelu(ev.x + edv.x)); m1 = fmaxf(m1, lrelu(ev.y + edv.y));
    m2 = fmaxf(m2, lrelu(ev.z + edv.z)); m3 = fmaxf(m3, lrelu(ev.w + edv.w));
  }
#pragma unroll
  for (int off = 32; off; off >>= 1) {
    m0 = fmaxf(m0, __shfl_xor(m0, off)); m1 = fmaxf(m1, __shfl_xor(m1, off));
    m2 = fmaxf(m2, __shfl_xor(m2, off)); m3 = fmaxf(m3, __shfl_xor(m3, off));
  }
  float s0 = 0.f, s1 = 0.f, s2 = 0.f, s3 = 0.f;
  float4 p0, p1;
  if (v0) {
    p0.x = __expf(lrelu(e0.x + edv.x) - m0); p0.y = __expf(lrelu(e0.y + edv.y) - m1);
    p0.z = __expf(lrelu(e0.z + edv.z) - m2); p0.w = __expf(lrelu(e0.w + edv.w) - m3);
    s0 += p0.x; s1 += p0.y; s2 += p0.z; s3 += p0.w;
  }
  if (v1) {
    p1.x = __expf(lrelu(e1.x + edv.x) - m0); p1.y = __expf(lrelu(e1.y + edv.y) - m1);
    p1.z = __expf(lrelu(e1.z + edv.z) - m2); p1.w = __expf(lrelu(e1.w + edv.w) - m3);
    s0 += p1.x; s1 += p1.y; s2 += p1.z; s3 += p1.w;
  }
  for (int j = j1 + 64; j < end; j += 64) {
    float4 ev = es4[col[j]];
    s0 += __expf(lrelu(ev.x + edv.x) - m0); s1 += __expf(lrelu(ev.y + edv.y) - m1);
    s2 += __expf(lrelu(ev.z + edv.z) - m2); s3 += __expf(lrelu(ev.w + edv.w) - m3);
  }
#pragma unroll
  for (int off = 32; off; off >>= 1) {
    s0 += __shfl_xor(s0, off); s1 += __shfl_xor(s1, off);
    s2 += __shfl_xor(s2, off); s3 += __shfl_xor(s3, off);
  }
  float i0 = 1.0f / s0, i1 = 1.0f / s1, i2 = 1.0f / s2, i3 = 1.0f / s3;
  if (v0) {
    uint2 w; w.x = pack2h(p0.x * i0, p0.y * i1); w.y = pack2h(p0.z * i2, p0.w * i3);
    *(uint2*)&alphaH[(size_t)j0 * 4] = w;
  }
  if (v1) {
    uint2 w; w.x = pack2h(p1.x * i0, p1.y * i1); w.y = pack2h(p1.z * i2, p1.w * i3);
    *(uint2*)&alphaH[(size_t)j1 * 4] = w;
  }
  for (int j = j1 + 64; j < end; j += 64) {
    float4 ev = es4[col[j]];
    uint2 w;
    w.x = pack2h(__expf(lrelu(ev.x + edv.x) - m0) * i0, __expf(lrelu(ev.y + edv.y) - m1) * i1);
    w.y = pack2h(__expf(lrelu(ev.z + edv.z) - m2) * i2, __expf(lrelu(ev.w + edv.w) - m3) * i3);
    *(uint2*)&alphaH[(size_t)j * 4] = w;
  }
}

// ---------------- weighted aggregation + bias + ELU ----------------
// one wave per destination node; lane owns adjacent features 2l, 2l+1 (head = l>>4).
__global__ __launch_bounds__(256) void agg_kernel(const __half* __restrict__ h,
                                                  const __half* __restrict__ alphaH,
                                                  const int* __restrict__ row_ptr,
                                                  const int* __restrict__ col,
                                                  const float* __restrict__ bias,
                                                  float* __restrict__ out) {
  int wid = (blockIdx.x * 256 + threadIdx.x) >> 6;
  if (wid >= NN) return;
  int lane = threadIdx.x & 63;
  int start = row_ptr[wid], end = row_ptr[wid + 1];
  const int hd = lane >> 4;
  float acc0 = 0.f, acc1 = 0.f;
  int j = start;
  for (; j + 4 <= end; j += 4) {
    int s0 = col[j], s1 = col[j + 1], s2 = col[j + 2], s3 = col[j + 3];
    float w0 = __half2float(alphaH[(size_t)j * 4 + hd]);
    float w1 = __half2float(alphaH[(size_t)(j + 1) * 4 + hd]);
    float w2 = __half2float(alphaH[(size_t)(j + 2) * 4 + hd]);
    float w3 = __half2float(alphaH[(size_t)(j + 3) * 4 + hd]);
    __half2 v0 = *(const __half2*)&h[(size_t)s0 * 128 + 2 * lane];
    __half2 v1 = *(const __half2*)&h[(size_t)s1 * 128 + 2 * lane];
    __half2 v2 = *(const __half2*)&h[(size_t)s2 * 128 + 2 * lane];
    __half2 v3 = *(const __half2*)&h[(size_t)s3 * 128 + 2 * lane];
    float2 f0 = __half22float2(v0), f1 = __half22float2(v1);
    float2 f2 = __half22float2(v2), f3 = __half22float2(v3);
    acc0 += f0.x * w0; acc1 += f0.y * w0;
    acc0 += f1.x * w1; acc1 += f1.y * w1;
    acc0 += f2.x * w2; acc1 += f2.y * w2;
    acc0 += f3.x * w3; acc1 += f3.y * w3;
  }
  for (; j < end; ++j) {
    int s = col[j];
    float w = __half2float(alphaH[(size_t)j * 4 + hd]);
    __half2 v = *(const __half2*)&h[(size_t)s * 128 + 2 * lane];
    float2 f = __half22float2(v);
    acc0 += f.x * w; acc1 += f.y * w;
  }
  float o0 = acc0 + bias[2 * lane];
  float o1 = acc1 + bias[2 * lane + 1];
  float2 o; o.x = elu1(o0); o.y = elu1(o1);
  *(float2*)&out[(size_t)wid * 128 + 2 * lane] = o;
}

extern "C" void kernel_launch(void* const* d_in, const int* in_sizes, int n_in,
                              void* d_out, int out_size, void* d_ws, size_t ws_size,
                              hipStream_t stream) {
  const float* x   = (const float*)d_in[0];
  const int*   ei  = (const int*)d_in[1];   // [2, E] int32
  const float* W1  = (const float*)d_in[2];
  const float* as1 = (const float*)d_in[3];
  const float* ad1 = (const float*)d_in[4];
  const float* b1  = (const float*)d_in[5];
  const float* W2  = (const float*)d_in[6];
  const float* as2 = (const float*)d_in[7];
  const float* ad2 = (const float*)d_in[8];
  const float* b2  = (const float*)d_in[9];

  char* ws = (char*)d_ws;
  __half* h     = (__half*)(ws);                 // 12,800,000 B (fp16 h table)
  __half* alph  = (__half*)(ws + 12800000);      //  6,800,000 B (ET * 8, normalized fp16x4)
  float*  es    = (float*) (ws + 19600000);      //    800,000 B
  float*  ed    = (float*) (ws + 20400000);      //    800,000 B
  int*    cnt   = (int*)   (ws + 21200000);      //    200,000 B
  int*    rowp  = (int*)   (ws + 21400000);      //    200,016 B
  int*    col   = (int*)   (ws + 21600064);      //  3,400,000 B
  int*    rank  = (int*)   (ws + 25000064);      //  3,400,000 B
  short*  wt1h  = (short*) (ws + 28400064);      //     65,536 B
  short*  wt1l  = (short*) (ws + 28465600);      //     65,536 B
  short*  wt2h  = (short*) (ws + 28531136);      //     32,768 B
  short*  wt2l  = (short*) (ws + 28563904);      //     32,768 B
  float*  h2    = (float*) d_out;                // layer-1 output scratch (overwritten by agg2)

  // ---- W split/transpose prep ----
  wprep_kernel<<<128, 256, 0, stream>>>(W1, wt1h, wt1l, 256);
  wprep_kernel<<<64, 256, 0, stream>>>(W2, wt2h, wt2l, 128);

  // ---- CSR by destination (rank trick: single atomic pass, atomic-free scatter) ----
  hipMemsetAsync(cnt, 0, NN * sizeof(int), stream);
  int egrid = (ET + 255) / 256;
  count_rank_kernel<<<egrid, 256, 0, stream>>>(ei, cnt, rank);
  scan_kernel<<<1, 1024, 0, stream>>>(cnt, rowp, NN);
  scatter_kernel<<<egrid, 256, 0, stream>>>(ei, rowp, rank, col);

  int ngrid = (NN + 3) / 4;        // one 64-lane wave per node
  int ggrid = (NN + 63) / 64;      // 782 blocks

  // ---- layer 1 ----
  gemm_mfma<256><<<ggrid, 256, 0, stream>>>(x, wt1h, wt1l, as1, ad1, h, es, ed);
  alpha_kernel<<<ngrid, 256, 0, stream>>>((const float4*)es, (const float4*)ed, rowp, col, alph);
  agg_kernel<<<ngrid, 256, 0, stream>>>(h, alph, rowp, col, b1, h2);

  // ---- layer 2 ----
  gemm_mfma<128><<<ggrid, 256, 0, stream>>>(h2, wt2h, wt2l, as2, ad2, h, es, ed);
  alpha_kernel<<<ngrid, 256, 0, stream>>>((const float4*)es, (const float4*)ed, rowp, col, alph);
  agg_kernel<<<ngrid, 256, 0, stream>>>(h, alph, rowp, col, b2, (float*)d_out);
}

// Round 7
// 209.674 us; speedup vs baseline: 3.0726x; 1.2168x over previous
//
#include <hip/hip_runtime.h>
#include <hip/hip_fp16.h>
#include <type_traits>

#define NN 50000
#define NE 800000
#define ET (NE + NN)
#define NEG 0.2f

typedef __attribute__((ext_vector_type(4))) float f32x4;
typedef __attribute__((ext_vector_type(8))) short s16x8;

__device__ __forceinline__ float lrelu(float x) { return x > 0.0f ? x : NEG * x; }
__device__ __forceinline__ float elu1(float x) { return x > 0.0f ? x : __expf(x) - 1.0f; }
__device__ __forceinline__ unsigned short f2bf(float f) {  // fp32 -> bf16 RNE
  unsigned u = __float_as_uint(f);
  u += 0x7FFFu + ((u >> 16) & 1u);
  return (unsigned short)(u >> 16);
}
__device__ __forceinline__ float bf2f(unsigned short h) {
  return __uint_as_float(((unsigned)h) << 16);
}

// ---------------- W prep: split fp32 W[K][128] into hi/lo bf16, TRANSPOSED [128][K] ----------------
__global__ void wprep_kernel(const float* __restrict__ W, short* __restrict__ Wth,
                             short* __restrict__ Wtl, int Kdim) {
  int idx = blockIdx.x * 256 + threadIdx.x;
  if (idx >= Kdim * 128) return;
  int k = idx >> 7, n = idx & 127;
  float w = W[idx];
  unsigned short h = f2bf(w);
  unsigned short l = f2bf(w - bf2f(h));
  Wth[n * Kdim + k] = (short)h;
  Wtl[n * Kdim + k] = (short)l;
}

// ---------------- MFMA GEMM (split-bf16, 3 terms) + fused per-node logits ----------------
// A dtype templated: fp32 (layer 1 input x) or fp16 (layer-1 activations h2).
// fp16 -> (hi,lo) bf16 split is EXACT (11-bit mantissa fits in 8+? residual <= bf16).
template<int K, typename AT>
__global__ __launch_bounds__(256) void gemm_mfma(const AT* __restrict__ A,
                                                 const short* __restrict__ Bth,
                                                 const short* __restrict__ Btl,
                                                 const float* __restrict__ a_s,
                                                 const float* __restrict__ a_d,
                                                 __half* __restrict__ outh,
                                                 float* __restrict__ es,
                                                 float* __restrict__ ed) {
  constexpr int NSTEP = K / 32;
  __shared__ short Ah[64 * 32], Al[64 * 32];
  __shared__ short Bh[128 * 32], Bl[128 * 32];
  const int tid = threadIdx.x;
  const int lane = tid & 63;
  const int wv = tid >> 6;
  const int wm = wv >> 1, wn = wv & 1;
  const int row0 = blockIdx.x * 64;
  const int srow = tid >> 2;   // staging row 0..63
  const int skc = tid & 3;     // staging k-chunk of 8

  f32x4 acc[2][4];
#pragma unroll
  for (int i = 0; i < 2; ++i)
#pragma unroll
    for (int j = 0; j < 4; ++j) acc[i][j] = (f32x4){0.f, 0.f, 0.f, 0.f};

  for (int s = 0; s < NSTEP; ++s) {
    __syncthreads();
    {  // stage A: 8 elems -> 8 (hi,lo) bf16 pairs
      int grow = row0 + srow; grow = grow < NN ? grow : NN - 1;  // clamp; stores guarded
      const AT* ap = &A[(size_t)grow * K + s * 32 + skc * 8];
      float xs[8];
      if constexpr (std::is_same_v<AT, float>) {
        float4 x0 = *(const float4*)ap;
        float4 x1 = *(const float4*)(ap + 4);
        xs[0]=x0.x; xs[1]=x0.y; xs[2]=x0.z; xs[3]=x0.w;
        xs[4]=x1.x; xs[5]=x1.y; xs[6]=x1.z; xs[7]=x1.w;
      } else {
        int4 raw = *(const int4*)ap;  // 8 halfs
        const __half2* hv = (const __half2*)&raw;
#pragma unroll
        for (int q = 0; q < 4; ++q) {
          float2 f = __half22float2(hv[q]);
          xs[2 * q] = f.x; xs[2 * q + 1] = f.y;
        }
      }
      int hi[4], lo[4];
#pragma unroll
      for (int q = 0; q < 4; ++q) {
        unsigned short h0 = f2bf(xs[2 * q]);
        unsigned short l0 = f2bf(xs[2 * q] - bf2f(h0));
        unsigned short h1 = f2bf(xs[2 * q + 1]);
        unsigned short l1 = f2bf(xs[2 * q + 1] - bf2f(h1));
        hi[q] = (int)(((unsigned)h1 << 16) | h0);
        lo[q] = (int)(((unsigned)l1 << 16) | l0);
      }
      *(int4*)&Ah[srow * 32 + skc * 8] = make_int4(hi[0], hi[1], hi[2], hi[3]);
      *(int4*)&Al[srow * 32 + skc * 8] = make_int4(lo[0], lo[1], lo[2], lo[3]);
    }
#pragma unroll
    for (int rr = 0; rr < 2; ++rr) {  // stage B (pre-split, pre-transposed bf16)
      int n = srow + rr * 64;
      *(int4*)&Bh[n * 32 + skc * 8] = *(const int4*)&Bth[(size_t)n * K + s * 32 + skc * 8];
      *(int4*)&Bl[n * 32 + skc * 8] = *(const int4*)&Btl[(size_t)n * K + s * 32 + skc * 8];
    }
    __syncthreads();
    const int fr = lane & 15;
    const int fk = (lane >> 4) * 8;
    s16x8 ah[2], al[2], bh[4], bl[4];
#pragma unroll
    for (int mf = 0; mf < 2; ++mf) {
      int r = wm * 32 + mf * 16 + fr;
      ah[mf] = *(const s16x8*)&Ah[r * 32 + fk];
      al[mf] = *(const s16x8*)&Al[r * 32 + fk];
    }
#pragma unroll
    for (int nf = 0; nf < 4; ++nf) {
      int n = wn * 64 + nf * 16 + fr;
      bh[nf] = *(const s16x8*)&Bh[n * 32 + fk];
      bl[nf] = *(const s16x8*)&Bl[n * 32 + fk];
    }
#pragma unroll
    for (int mf = 0; mf < 2; ++mf)
#pragma unroll
      for (int nf = 0; nf < 4; ++nf) {
        acc[mf][nf] = __builtin_amdgcn_mfma_f32_16x16x32_bf16(ah[mf], bh[nf], acc[mf][nf], 0, 0, 0);
        acc[mf][nf] = __builtin_amdgcn_mfma_f32_16x16x32_bf16(ah[mf], bl[nf], acc[mf][nf], 0, 0, 0);
        acc[mf][nf] = __builtin_amdgcn_mfma_f32_16x16x32_bf16(al[mf], bh[nf], acc[mf][nf], 0, 0, 0);
      }
  }

  // epilogue: C/D layout col=lane&15, row=(lane>>4)*4+r
  const int fr = lane & 15;
  const int fg = lane >> 4;
  float asr[4], adr[4];
#pragma unroll
  for (int nf = 0; nf < 4; ++nf) {
    int c = wn * 64 + nf * 16 + fr;
    asr[nf] = a_s[c]; adr[nf] = a_d[c];
  }
#pragma unroll
  for (int mf = 0; mf < 2; ++mf) {
#pragma unroll
    for (int r = 0; r < 4; ++r) {
      int row = row0 + wm * 32 + mf * 16 + fg * 4 + r;
      float sp0 = acc[mf][0][r] * asr[0] + acc[mf][1][r] * asr[1];  // head wn*2
      float sp1 = acc[mf][2][r] * asr[2] + acc[mf][3][r] * asr[3];  // head wn*2+1
      float dp0 = acc[mf][0][r] * adr[0] + acc[mf][1][r] * adr[1];
      float dp1 = acc[mf][2][r] * adr[2] + acc[mf][3][r] * adr[3];
#pragma unroll
      for (int off = 1; off < 16; off <<= 1) {  // reduce over the 16 cols
        sp0 += __shfl_xor(sp0, off); sp1 += __shfl_xor(sp1, off);
        dp0 += __shfl_xor(dp0, off); dp1 += __shfl_xor(dp1, off);
      }
      if (row < NN) {
#pragma unroll
        for (int nf = 0; nf < 4; ++nf)
          outh[(size_t)row * 128 + wn * 64 + nf * 16 + fr] = __float2half(acc[mf][nf][r]);
        if (fr == 0) {
          es[row * 4 + wn * 2 + 0] = sp0;
          es[row * 4 + wn * 2 + 1] = sp1;
          ed[row * 4 + wn * 2 + 0] = dp0;
          ed[row * 4 + wn * 2 + 1] = dp1;
        }
      }
    }
  }
}

// ---------------- CSR build: count + rank (the only atomic pass) ----------------
__global__ void count_rank_kernel(const int* __restrict__ ei, int* __restrict__ cnt,
                                  int* __restrict__ rank) {
  int e = blockIdx.x * blockDim.x + threadIdx.x;
  if (e >= ET) return;
  int dst = (e < NE) ? ei[NE + e] : (e - NE);
  rank[e] = atomicAdd(&cnt[dst], 1);
}

__global__ __launch_bounds__(1024) void scan_kernel(const int* __restrict__ cnt,
                                                    int* __restrict__ row_ptr, int n) {
  __shared__ int wsum[16];
  __shared__ int blocktot_s;
  __shared__ int carry_s;
  const int lane = threadIdx.x & 63;
  const int wv = threadIdx.x >> 6;
  if (threadIdx.x == 0) carry_s = 0;
  __syncthreads();
  for (int base = 0; base < n; base += 4096) {
    int idx = base + threadIdx.x * 4;
    int4 v = {0, 0, 0, 0};
    if (idx < n) v = *(const int4*)&cnt[idx];
    int tsum = v.x + v.y + v.z + v.w;
    int sc = tsum;
#pragma unroll
    for (int off = 1; off < 64; off <<= 1) {
      int t = __shfl_up(sc, off);
      if (lane >= off) sc += t;
    }
    if (lane == 63) wsum[wv] = sc;
    __syncthreads();
    if (wv == 0 && lane < 16) {
      int ws = wsum[lane];
      int si = ws;
#pragma unroll
      for (int off = 1; off < 16; off <<= 1) {
        int t = __shfl_up(si, off);
        if (lane >= off) si += t;
      }
      wsum[lane] = si - ws;
      if (lane == 15) blocktot_s = si;
    }
    __syncthreads();
    int run = carry_s + wsum[wv] + (sc - tsum);
    if (idx < n) {
      int4 o;
      o.x = run; o.y = run + v.x; o.z = o.y + v.y; o.w = o.z + v.z;
      *(int4*)&row_ptr[idx] = o;
    }
    __syncthreads();
    if (threadIdx.x == 0) carry_s += blocktot_s;
    __syncthreads();
  }
  if (threadIdx.x == 0) row_ptr[n] = carry_s;
}

// atomic-free scatter: position = row_ptr[dst] + rank[e]
__global__ void scatter_kernel(const int* __restrict__ ei, const int* __restrict__ row_ptr,
                               const int* __restrict__ rank, int* __restrict__ col) {
  int e = blockIdx.x * blockDim.x + threadIdx.x;
  if (e >= ET) return;
  int src, dst;
  if (e < NE) { src = ei[e]; dst = ei[NE + e]; } else { src = dst = e - NE; }
  col[row_ptr[dst] + rank[e]] = src;
}

// ---------------- FUSED softmax + aggregation + bias + ELU ----------------
// One wave per destination node.
// Pass A (lane-parallel over <=128 neighbors): gather es4, reduce max/sum via shfl,
//   store normalized fp32 weights + col indices in per-wave LDS (no __syncthreads:
//   LDS regions are wave-private).
// Pass B (feature-parallel): lane owns features 2l,2l+1 (head l>>4); weights from LDS.
// Degree > 128: overflow edges recompute weight inline (broadcast gather; ~never).
template<typename OT>
__global__ __launch_bounds__(256) void agg_fused(const __half* __restrict__ h,
                                                 const float4* __restrict__ es4,
                                                 const float4* __restrict__ ed4,
                                                 const int* __restrict__ row_ptr,
                                                 const int* __restrict__ col,
                                                 const float* __restrict__ bias,
                                                 OT* __restrict__ out) {
  __shared__ float wc[4][512];  // [wave][edge*4+head] normalized weights
  __shared__ int   cc[4][128];  // [wave][edge] source index
  int wid = (blockIdx.x * 256 + threadIdx.x) >> 6;
  if (wid >= NN) return;
  const int lane = threadIdx.x & 63;
  const int wv = (threadIdx.x >> 6) & 3;
  const int start = row_ptr[wid], end = row_ptr[wid + 1];
  const int deg = end - start;
  const float4 edv = ed4[wid];

  // ---- pass A: softmax weights ----
  const bool v0 = lane < deg, v1 = lane + 64 < deg;
  int c0 = 0, c1 = 0;
  float4 e0, e1;
  if (v0) { c0 = col[start + lane]; e0 = es4[c0]; }
  if (v1) { c1 = col[start + lane + 64]; e1 = es4[c1]; }
  float m0 = -1e30f, m1 = -1e30f, m2 = -1e30f, m3 = -1e30f;
  if (v0) {
    m0 = fmaxf(m0, lrelu(e0.x + edv.x)); m1 = fmaxf(m1, lrelu(e0.y + edv.y));
    m2 = fmaxf(m2, lrelu(e0.z + edv.z)); m3 = fmaxf(m3, lrelu(e0.w + edv.w));
  }
  if (v1) {
    m0 = fmaxf(m0, lrelu(e1.x + edv.x)); m1 = fmaxf(m1, lrelu(e1.y + edv.y));
    m2 = fmaxf(m2, lrelu(e1.z + edv.z)); m3 = fmaxf(m3, lrelu(e1.w + edv.w));
  }
  for (int j = start + lane + 128; j < end; j += 64) {  // rare
    float4 ev = es4[col[j]];
    m0 = fmaxf(m0, lrelu(ev.x + edv.x)); m1 = fmaxf(m1, lrelu(ev.y + edv.y));
    m2 = fmaxf(m2, lrelu(ev.z + edv.z)); m3 = fmaxf(m3, lrelu(ev.w + edv.w));
  }
#pragma unroll
  for (int off = 32; off; off >>= 1) {
    m0 = fmaxf(m0, __shfl_xor(m0, off)); m1 = fmaxf(m1, __shfl_xor(m1, off));
    m2 = fmaxf(m2, __shfl_xor(m2, off)); m3 = fmaxf(m3, __shfl_xor(m3, off));
  }
  float s0 = 0.f, s1 = 0.f, s2 = 0.f, s3 = 0.f;
  float4 p0, p1;
  if (v0) {
    p0.x = __expf(lrelu(e0.x + edv.x) - m0); p0.y = __expf(lrelu(e0.y + edv.y) - m1);
    p0.z = __expf(lrelu(e0.z + edv.z) - m2); p0.w = __expf(lrelu(e0.w + edv.w) - m3);
    s0 += p0.x; s1 += p0.y; s2 += p0.z; s3 += p0.w;
  }
  if (v1) {
    p1.x = __expf(lrelu(e1.x + edv.x) - m0); p1.y = __expf(lrelu(e1.y + edv.y) - m1);
    p1.z = __expf(lrelu(e1.z + edv.z) - m2); p1.w = __expf(lrelu(e1.w + edv.w) - m3);
    s0 += p1.x; s1 += p1.y; s2 += p1.z; s3 += p1.w;
  }
  for (int j = start + lane + 128; j < end; j += 64) {
    float4 ev = es4[col[j]];
    s0 += __expf(lrelu(ev.x + edv.x) - m0); s1 += __expf(lrelu(ev.y + edv.y) - m1);
    s2 += __expf(lrelu(ev.z + edv.z) - m2); s3 += __expf(lrelu(ev.w + edv.w) - m3);
  }
#pragma unroll
  for (int off = 32; off; off >>= 1) {
    s0 += __shfl_xor(s0, off); s1 += __shfl_xor(s1, off);
    s2 += __shfl_xor(s2, off); s3 += __shfl_xor(s3, off);
  }
  const float i0 = 1.0f / s0, i1 = 1.0f / s1, i2 = 1.0f / s2, i3 = 1.0f / s3;
  if (v0) {
    float4 w; w.x = p0.x * i0; w.y = p0.y * i1; w.z = p0.z * i2; w.w = p0.w * i3;
    *(float4*)&wc[wv][lane * 4] = w;
    cc[wv][lane] = c0;
  }
  if (v1) {
    float4 w; w.x = p1.x * i0; w.y = p1.y * i1; w.z = p1.z * i2; w.w = p1.w * i3;
    *(float4*)&wc[wv][(lane + 64) * 4] = w;
    cc[wv][lane + 64] = c1;
  }

  // ---- pass B: weighted aggregation ----
  const int hd = lane >> 4;
  float acc0 = 0.f, acc1 = 0.f;
  const int deg1 = deg < 128 ? deg : 128;
  int jj = 0;
  for (; jj + 4 <= deg1; jj += 4) {
    int t0 = cc[wv][jj], t1 = cc[wv][jj + 1], t2 = cc[wv][jj + 2], t3 = cc[wv][jj + 3];
    float w0 = wc[wv][jj * 4 + hd];
    float w1 = wc[wv][(jj + 1) * 4 + hd];
    float w2 = wc[wv][(jj + 2) * 4 + hd];
    float w3 = wc[wv][(jj + 3) * 4 + hd];
    __half2 q0 = *(const __half2*)&h[(size_t)t0 * 128 + 2 * lane];
    __half2 q1 = *(const __half2*)&h[(size_t)t1 * 128 + 2 * lane];
    __half2 q2 = *(const __half2*)&h[(size_t)t2 * 128 + 2 * lane];
    __half2 q3 = *(const __half2*)&h[(size_t)t3 * 128 + 2 * lane];
    float2 f0 = __half22float2(q0), f1 = __half22float2(q1);
    float2 f2 = __half22float2(q2), f3 = __half22float2(q3);
    acc0 += f0.x * w0; acc1 += f0.y * w0;
    acc0 += f1.x * w1; acc1 += f1.y * w1;
    acc0 += f2.x * w2; acc1 += f2.y * w2;
    acc0 += f3.x * w3; acc1 += f3.y * w3;
  }
  for (; jj < deg1; ++jj) {
    int t = cc[wv][jj];
    float w = wc[wv][jj * 4 + hd];
    __half2 q = *(const __half2*)&h[(size_t)t * 128 + 2 * lane];
    float2 f = __half22float2(q);
    acc0 += f.x * w; acc1 += f.y * w;
  }
  if (deg > 128) {  // overflow: recompute weight inline (broadcast gather)
    float mh = hd == 0 ? m0 : hd == 1 ? m1 : hd == 2 ? m2 : m3;
    float ih = hd == 0 ? i0 : hd == 1 ? i1 : hd == 2 ? i2 : i3;
    float eh = hd == 0 ? edv.x : hd == 1 ? edv.y : hd == 2 ? edv.z : edv.w;
    for (int j = start + 128; j < end; ++j) {
      int t = col[j];
      const float* ep = (const float*)&es4[t];
      float w = __expf(lrelu(ep[hd] + eh) - mh) * ih;
      __half2 q = *(const __half2*)&h[(size_t)t * 128 + 2 * lane];
      float2 f = __half22float2(q);
      acc0 += f.x * w; acc1 += f.y * w;
    }
  }
  float o0 = elu1(acc0 + bias[2 * lane]);
  float o1 = elu1(acc1 + bias[2 * lane + 1]);
  if constexpr (std::is_same_v<OT, float>) {
    float2 o; o.x = o0; o.y = o1;
    *(float2*)&out[(size_t)wid * 128 + 2 * lane] = o;
  } else {
    *(__half2*)&out[(size_t)wid * 128 + 2 * lane] = __floats2half2_rn(o0, o1);
  }
}

extern "C" void kernel_launch(void* const* d_in, const int* in_sizes, int n_in,
                              void* d_out, int out_size, void* d_ws, size_t ws_size,
                              hipStream_t stream) {
  const float* x   = (const float*)d_in[0];
  const int*   ei  = (const int*)d_in[1];   // [2, E] int32
  const float* W1  = (const float*)d_in[2];
  const float* as1 = (const float*)d_in[3];
  const float* ad1 = (const float*)d_in[4];
  const float* b1  = (const float*)d_in[5];
  const float* W2  = (const float*)d_in[6];
  const float* as2 = (const float*)d_in[7];
  const float* ad2 = (const float*)d_in[8];
  const float* b2  = (const float*)d_in[9];

  char* ws = (char*)d_ws;
  __half* h     = (__half*)(ws);                 // 12,800,000 B (fp16 gather table)
  __half* h2    = (__half*)(ws + 12800000);      // 12,800,000 B (fp16 layer-1 out)
  float*  es    = (float*) (ws + 25600000);      //    800,000 B
  float*  ed    = (float*) (ws + 26400000);      //    800,000 B
  int*    cnt   = (int*)   (ws + 27200000);      //    200,000 B
  int*    rowp  = (int*)   (ws + 27400000);      //    200,016 B
  int*    col   = (int*)   (ws + 27600064);      //  3,400,000 B
  int*    rank  = (int*)   (ws + 31000064);      //  3,400,000 B
  short*  wt1h  = (short*) (ws + 34400064);      //     65,536 B
  short*  wt1l  = (short*) (ws + 34465600);      //     65,536 B
  short*  wt2h  = (short*) (ws + 34531136);      //     32,768 B
  short*  wt2l  = (short*) (ws + 34563904);      //     32,768 B

  // ---- W split/transpose prep ----
  wprep_kernel<<<128, 256, 0, stream>>>(W1, wt1h, wt1l, 256);
  wprep_kernel<<<64, 256, 0, stream>>>(W2, wt2h, wt2l, 128);

  // ---- CSR by destination (rank trick: single atomic pass, atomic-free scatter) ----
  hipMemsetAsync(cnt, 0, NN * sizeof(int), stream);
  int egrid = (ET + 255) / 256;
  count_rank_kernel<<<egrid, 256, 0, stream>>>(ei, cnt, rank);
  scan_kernel<<<1, 1024, 0, stream>>>(cnt, rowp, NN);
  scatter_kernel<<<egrid, 256, 0, stream>>>(ei, rowp, rank, col);

  int ngrid = (NN + 3) / 4;        // one 64-lane wave per node
  int ggrid = (NN + 63) / 64;      // 782 blocks

  // ---- layer 1 ----
  gemm_mfma<256, float><<<ggrid, 256, 0, stream>>>(x, wt1h, wt1l, as1, ad1, h, es, ed);
  agg_fused<__half><<<ngrid, 256, 0, stream>>>(h, (const float4*)es, (const float4*)ed,
                                               rowp, col, b1, h2);

  // ---- layer 2 ----
  gemm_mfma<128, __half><<<ggrid, 256, 0, stream>>>(h2, wt2h, wt2l, as2, ad2, h, es, ed);
  agg_fused<float><<<ngrid, 256, 0, stream>>>(h, (const float4*)es, (const float4*)ed,
                                              rowp, col, b2, (float*)d_out);
}